// Round 1
// baseline (1712.922 us; speedup 1.0000x reference)
//
#include <hip/hip_runtime.h>
#include <math.h>

#define NH 16
#define HD 64
#define DM 1024
#define BB 2
#define SS 2048
#define MROWS (BB*SS)   // 4096

// ---------------------------------------------------------------------------
// Tiled fp32 GEMM core: Y[r][c] = sum_k A[r][k] * W[c][k] + bias[c]
// BM=BN=128, BK=16, block=256 threads, 8x8 micro-tile (split 64-offset groups)
// A: points at row m0 (stride 1024). W: points at row n0 (stride 1024).
// Yrowbase: &Y[m0][n0-global], row stride ldy.
// ---------------------------------------------------------------------------
__device__ __forceinline__ void gemm128(const float* __restrict__ A,
                                        const float* __restrict__ W,
                                        const float* __restrict__ bias,
                                        float* __restrict__ Yrowbase,
                                        int ldy)
{
    __shared__ float As[128][17];
    __shared__ float Bs[128][17];

    const int tid = threadIdx.x;
    const int tx = tid & 15;        // 0..15  (cols)
    const int ty = tid >> 4;        // 0..15  (rows)

    float acc[8][8];
#pragma unroll
    for (int i = 0; i < 8; ++i)
#pragma unroll
        for (int j = 0; j < 8; ++j) acc[i][j] = 0.f;

    for (int k0 = 0; k0 < 1024; k0 += 16) {
        // stage A-tile and W-tile (128x16 each) via float4 loads
#pragma unroll
        for (int u = 0; u < 2; ++u) {
            const int f   = tid + u * 256;        // 0..511
            const int row = f >> 2;
            const int c4  = (f & 3) * 4;
            const float4 av = *(const float4*)(A + (size_t)row * 1024 + k0 + c4);
            As[row][c4 + 0] = av.x; As[row][c4 + 1] = av.y;
            As[row][c4 + 2] = av.z; As[row][c4 + 3] = av.w;
            const float4 wv = *(const float4*)(W + (size_t)row * 1024 + k0 + c4);
            Bs[row][c4 + 0] = wv.x; Bs[row][c4 + 1] = wv.y;
            Bs[row][c4 + 2] = wv.z; Bs[row][c4 + 3] = wv.w;
        }
        __syncthreads();

#pragma unroll
        for (int kk = 0; kk < 16; ++kk) {
            float a[8], b[8];
#pragma unroll
            for (int i = 0; i < 4; ++i) {
                a[i]     = As[ty * 4 + i][kk];
                a[i + 4] = As[64 + ty * 4 + i][kk];
            }
#pragma unroll
            for (int j = 0; j < 4; ++j) {
                b[j]     = Bs[tx * 4 + j][kk];
                b[j + 4] = Bs[64 + tx * 4 + j][kk];
            }
#pragma unroll
            for (int i = 0; i < 8; ++i)
#pragma unroll
                for (int j = 0; j < 8; ++j)
                    acc[i][j] += a[i] * b[j];
        }
        __syncthreads();
    }

    // epilogue: float4 stores, add bias
#pragma unroll
    for (int i = 0; i < 8; ++i) {
        const int row = (i < 4) ? (ty * 4 + i) : (64 + ty * 4 + (i - 4));
#pragma unroll
        for (int jg = 0; jg < 2; ++jg) {
            const int col = jg * 64 + tx * 4;
            float4 o;
            o.x = acc[i][jg * 4 + 0] + bias[col + 0];
            o.y = acc[i][jg * 4 + 1] + bias[col + 1];
            o.z = acc[i][jg * 4 + 2] + bias[col + 2];
            o.w = acc[i][jg * 4 + 3] + bias[col + 3];
            *(float4*)(Yrowbase + (size_t)row * ldy + col) = o;
        }
    }
}

// QKV projection: Y (4096 x 3072), cols [0,1024)=Q, [1024,2048)=K, [2048,3072)=V
__global__ __launch_bounds__(256)
void qkv_proj(const float* __restrict__ xq, const float* __restrict__ xk,
              const float* __restrict__ xv,
              const float* __restrict__ wq, const float* __restrict__ bq,
              const float* __restrict__ wk, const float* __restrict__ bk,
              const float* __restrict__ wv, const float* __restrict__ bv,
              float* __restrict__ Y)
{
    const int nblk = blockIdx.x;            // 0..23
    const int m0   = blockIdx.y * 128;      // 0..3968
    const int mat  = nblk >> 3;             // 0,1,2
    const int ncol = (nblk & 7) * 128;      // local col within matrix
    const float* A    = (mat == 0) ? xq : (mat == 1) ? xk : xv;
    const float* W    = ((mat == 0) ? wq : (mat == 1) ? wk : wv) + (size_t)ncol * 1024;
    const float* bias = ((mat == 0) ? bq : (mat == 1) ? bk : bv) + ncol;
    gemm128(A + (size_t)m0 * 1024, W, bias,
            Y + (size_t)m0 * 3072 + nblk * 128, 3072);
}

// Output projection: out (4096 x 1024) = Ain @ w_o^T + b_o
__global__ __launch_bounds__(256)
void out_proj(const float* __restrict__ Ain, const float* __restrict__ wo,
              const float* __restrict__ bo, float* __restrict__ out)
{
    const int n0 = blockIdx.x * 128;
    const int m0 = blockIdx.y * 128;
    gemm128(Ain + (size_t)m0 * 1024, wo + (size_t)n0 * 1024, bo + n0,
            out + (size_t)m0 * 1024 + n0, 1024);
}

// ---------------------------------------------------------------------------
// Flash attention: block = (b, h, 64-row q-tile), 4 waves x 16 rows.
// Kt[d][j] transposed+padded (conflict-free score reads), Vs[j][d] linear,
// P transposed through per-wave LDS for the PV step.
// key valid iff kg <= qg && kg < valid_len[b]   (key 0 always valid)
// ---------------------------------------------------------------------------
__global__ __launch_bounds__(256)
void attn_kernel(const float* __restrict__ qkv, const int* __restrict__ vlen,
                 float* __restrict__ aout)
{
    __shared__ float Qs[64][64];
    __shared__ float Kt[64][65];
    __shared__ float Vs[64][64];
    __shared__ float Ps[4][16][64];

    const int qt   = blockIdx.x;           // 0..31
    const int bh   = blockIdx.y;           // 0..31
    const int b    = bh >> 4;
    const int h    = bh & 15;
    const int q0   = qt * 64;
    const int vl   = vlen[b];
    const int tid  = threadIdx.x;
    const int w    = tid >> 6;             // wave 0..3
    const int lane = tid & 63;

    const float* qbase = qkv + (size_t)(b * SS) * 3072 + h * 64;
    const float* kbase = qbase + 1024;
    const float* vbase = qbase + 2048;

    // stage Q tile (64 rows x 64 dims)
#pragma unroll
    for (int u = 0; u < 4; ++u) {
        const int f  = tid + u * 256;      // 0..1023
        const int r  = f >> 4;
        const int d4 = (f & 15) * 4;
        *(float4*)&Qs[r][d4] =
            *(const float4*)(qbase + (size_t)(q0 + r) * 3072 + d4);
    }

    float m[16], l[16], O[16];
#pragma unroll
    for (int i = 0; i < 16; ++i) { m[i] = -INFINITY; l[i] = 0.f; O[i] = 0.f; }

    const int kmax   = min(q0 + 64, vl);       // exclusive key bound
    const int ntiles = (kmax + 63) >> 6;       // >= 1
    const float scale = 0.125f;                // 1/sqrt(64)
    const int rb = w << 4;                     // this wave's local row base

    for (int kt = 0; kt < ntiles; ++kt) {
        const int k0 = kt * 64;
        __syncthreads();   // previous tile's LDS fully consumed
        // stage K (transposed) and V
#pragma unroll
        for (int u = 0; u < 4; ++u) {
            const int f  = tid + u * 256;
            const int j  = f >> 4;
            const int d4 = (f & 15) * 4;
            const float4 kv = *(const float4*)(kbase + (size_t)(k0 + j) * 3072 + d4);
            Kt[d4 + 0][j] = kv.x; Kt[d4 + 1][j] = kv.y;
            Kt[d4 + 2][j] = kv.z; Kt[d4 + 3][j] = kv.w;
            *(float4*)&Vs[j][d4] =
                *(const float4*)(vbase + (size_t)(k0 + j) * 3072 + d4);
        }
        __syncthreads();

        // scores: lane j owns key k0+j;  s[i] = q_row(i) . K[j]
        float s[16];
#pragma unroll
        for (int i = 0; i < 16; ++i) s[i] = 0.f;
#pragma unroll
        for (int d4 = 0; d4 < 16; ++d4) {
            const float k0v = Kt[d4 * 4 + 0][lane];
            const float k1v = Kt[d4 * 4 + 1][lane];
            const float k2v = Kt[d4 * 4 + 2][lane];
            const float k3v = Kt[d4 * 4 + 3][lane];
#pragma unroll
            for (int i = 0; i < 16; ++i) {
                const float4 q4 = *(const float4*)&Qs[rb + i][d4 * 4];
                s[i] += q4.x * k0v + q4.y * k1v + q4.z * k2v + q4.w * k3v;
            }
        }

        // online softmax update, write P to per-wave LDS
        const int kg = k0 + lane;
#pragma unroll
        for (int i = 0; i < 16; ++i) {
            const int rg = q0 + rb + i;
            const bool ok = (kg <= rg) && (kg < vl);
            const float sv = ok ? s[i] * scale : -INFINITY;
            float t = sv;
#pragma unroll
            for (int off = 32; off; off >>= 1) t = fmaxf(t, __shfl_xor(t, off));
            const float mnew = fmaxf(m[i], t);   // finite after tile 0
            const float corr = __expf(m[i] - mnew);
            const float p    = __expf(sv - mnew);
            float ps = p;
#pragma unroll
            for (int off = 32; off; off >>= 1) ps += __shfl_xor(ps, off);
            l[i] = l[i] * corr + ps;
            O[i] *= corr;
            m[i] = mnew;
            Ps[w][i][lane] = p;
        }
        __syncthreads();   // order P writes before cross-lane P reads (safe)

        // PV: lane d owns output dim d;  O[i] += sum_j P[i][j] * V[j][d]
#pragma unroll
        for (int j4 = 0; j4 < 16; ++j4) {
            const float v0 = Vs[j4 * 4 + 0][lane];
            const float v1 = Vs[j4 * 4 + 1][lane];
            const float v2 = Vs[j4 * 4 + 2][lane];
            const float v3 = Vs[j4 * 4 + 3][lane];
#pragma unroll
            for (int i = 0; i < 16; ++i) {
                const float4 p4 = *(const float4*)&Ps[w][i][j4 * 4];
                O[i] += p4.x * v0 + p4.y * v1 + p4.z * v2 + p4.w * v3;
            }
        }
    }

    // write attention output (B,S,H*64) row-major
    float* obase = aout + (size_t)(b * SS) * 1024 + h * 64 + lane;
#pragma unroll
    for (int i = 0; i < 16; ++i) {
        const int rg = q0 + rb + i;
        obase[(size_t)rg * 1024] = O[i] / l[i];
    }
}

extern "C" void kernel_launch(void* const* d_in, const int* in_sizes, int n_in,
                              void* d_out, int out_size, void* d_ws, size_t ws_size,
                              hipStream_t stream) {
    const float* xq = (const float*)d_in[0];
    const float* xk = (const float*)d_in[1];
    const float* xv = (const float*)d_in[2];
    const int*   vl = (const int*)  d_in[3];
    const float* wq = (const float*)d_in[4];
    const float* bq = (const float*)d_in[5];
    const float* wk = (const float*)d_in[6];
    const float* bk = (const float*)d_in[7];
    const float* wv = (const float*)d_in[8];
    const float* bv = (const float*)d_in[9];
    const float* wo = (const float*)d_in[10];
    const float* bo = (const float*)d_in[11];

    float* qkvbuf = (float*)d_ws;                                  // 4096 x 3072
    float* abuf   = qkvbuf + (size_t)MROWS * 3072;                 // 4096 x 1024

    qkv_proj<<<dim3(24, 32), 256, 0, stream>>>(xq, xk, xv, wq, bq, wk, bk,
                                               wv, bv, qkvbuf);
    attn_kernel<<<dim3(SS / 64, BB * NH), 256, 0, stream>>>(qkvbuf, vl, abuf);
    out_proj<<<dim3(8, 32), 256, 0, stream>>>(abuf, wo, bo, (float*)d_out);
}

// Round 2
// 609.378 us; speedup vs baseline: 2.8109x; 2.8109x over previous
//
#include <hip/hip_runtime.h>
#include <math.h>

#define NH 16
#define HD 64
#define DM 1024
#define BB 2
#define SS 2048
#define MROWS (BB*SS)   // 4096

typedef __attribute__((ext_vector_type(8))) short bf16x8;
typedef __attribute__((ext_vector_type(4))) float f32x4;

__device__ __forceinline__ unsigned short f2bf(float x) {
    unsigned int u = __float_as_uint(x);
    u += 0x7fff + ((u >> 16) & 1);          // round-to-nearest-even
    return (unsigned short)(u >> 16);
}

// ---------------------------------------------------------------------------
// Tiled fp32 GEMM core: Y[r][c] = sum_k A[r][k] * W[c][k] + bias[c]
// BM=BN=128, BK=16, block=256 threads, 8x8 micro-tile.
// BF16OUT: epilogue converts to bf16 (ushort) instead of fp32.
// ---------------------------------------------------------------------------
template<bool BF16OUT>
__device__ __forceinline__ void gemm128(const float* __restrict__ A,
                                        const float* __restrict__ W,
                                        const float* __restrict__ bias,
                                        void* __restrict__ Yrowbase,
                                        int ldy)
{
    __shared__ float As[128][17];
    __shared__ float Bs[128][17];

    const int tid = threadIdx.x;
    const int tx = tid & 15;
    const int ty = tid >> 4;

    float acc[8][8];
#pragma unroll
    for (int i = 0; i < 8; ++i)
#pragma unroll
        for (int j = 0; j < 8; ++j) acc[i][j] = 0.f;

    for (int k0 = 0; k0 < 1024; k0 += 16) {
#pragma unroll
        for (int u = 0; u < 2; ++u) {
            const int f   = tid + u * 256;
            const int row = f >> 2;
            const int c4  = (f & 3) * 4;
            const float4 av = *(const float4*)(A + (size_t)row * 1024 + k0 + c4);
            As[row][c4 + 0] = av.x; As[row][c4 + 1] = av.y;
            As[row][c4 + 2] = av.z; As[row][c4 + 3] = av.w;
            const float4 wv = *(const float4*)(W + (size_t)row * 1024 + k0 + c4);
            Bs[row][c4 + 0] = wv.x; Bs[row][c4 + 1] = wv.y;
            Bs[row][c4 + 2] = wv.z; Bs[row][c4 + 3] = wv.w;
        }
        __syncthreads();

#pragma unroll
        for (int kk = 0; kk < 16; ++kk) {
            float a[8], b[8];
#pragma unroll
            for (int i = 0; i < 4; ++i) {
                a[i]     = As[ty * 4 + i][kk];
                a[i + 4] = As[64 + ty * 4 + i][kk];
            }
#pragma unroll
            for (int j = 0; j < 4; ++j) {
                b[j]     = Bs[tx * 4 + j][kk];
                b[j + 4] = Bs[64 + tx * 4 + j][kk];
            }
#pragma unroll
            for (int i = 0; i < 8; ++i)
#pragma unroll
                for (int j = 0; j < 8; ++j)
                    acc[i][j] += a[i] * b[j];
        }
        __syncthreads();
    }

#pragma unroll
    for (int i = 0; i < 8; ++i) {
        const int row = (i < 4) ? (ty * 4 + i) : (64 + ty * 4 + (i - 4));
#pragma unroll
        for (int jg = 0; jg < 2; ++jg) {
            const int col = jg * 64 + tx * 4;
            if constexpr (BF16OUT) {
                ushort4 o;
                o.x = f2bf(acc[i][jg * 4 + 0] + bias[col + 0]);
                o.y = f2bf(acc[i][jg * 4 + 1] + bias[col + 1]);
                o.z = f2bf(acc[i][jg * 4 + 2] + bias[col + 2]);
                o.w = f2bf(acc[i][jg * 4 + 3] + bias[col + 3]);
                *(ushort4*)((unsigned short*)Yrowbase + (size_t)row * ldy + col) = o;
            } else {
                float4 o;
                o.x = acc[i][jg * 4 + 0] + bias[col + 0];
                o.y = acc[i][jg * 4 + 1] + bias[col + 1];
                o.z = acc[i][jg * 4 + 2] + bias[col + 2];
                o.w = acc[i][jg * 4 + 3] + bias[col + 3];
                *(float4*)((float*)Yrowbase + (size_t)row * ldy + col) = o;
            }
        }
    }
}

// QKV projection -> bf16 buffer (4096 x 3072): [0,1024)=Q [1024,2048)=K [2048,3072)=V
__global__ __launch_bounds__(256)
void qkv_proj(const float* __restrict__ xq, const float* __restrict__ xk,
              const float* __restrict__ xv,
              const float* __restrict__ wq, const float* __restrict__ bq,
              const float* __restrict__ wk, const float* __restrict__ bk,
              const float* __restrict__ wv, const float* __restrict__ bv,
              unsigned short* __restrict__ Y)
{
    const int nblk = blockIdx.x;            // 0..23
    const int m0   = blockIdx.y * 128;
    const int mat  = nblk >> 3;
    const int ncol = (nblk & 7) * 128;
    const float* A    = (mat == 0) ? xq : (mat == 1) ? xk : xv;
    const float* W    = ((mat == 0) ? wq : (mat == 1) ? wk : wv) + (size_t)ncol * 1024;
    const float* bias = ((mat == 0) ? bq : (mat == 1) ? bk : bv) + ncol;
    gemm128<true>(A + (size_t)m0 * 1024, W, bias,
                  Y + (size_t)m0 * 3072 + nblk * 128, 3072);
}

__global__ __launch_bounds__(256)
void out_proj(const float* __restrict__ Ain, const float* __restrict__ wo,
              const float* __restrict__ bo, float* __restrict__ out)
{
    const int n0 = blockIdx.x * 128;
    const int m0 = blockIdx.y * 128;
    gemm128<false>(Ain + (size_t)m0 * 1024, wo + (size_t)n0 * 1024, bo + n0,
                   (float*)out + (size_t)m0 * 1024 + n0, 1024);
}

// ---------------------------------------------------------------------------
// MFMA flash attention: block = (b,h,64 q-rows), 4 waves; wave w owns q-rows
// [w*16, w*16+16). Per 64-key tile: S strip via 16x16x32 bf16 MFMA (4 frags x
// 2 k-halves), wave-parallel online softmax on the C-layout
// (col=lane&15=key, row=(lane>>4)*4+reg), P re-shaped to A-frag via per-wave
// padded LDS, PV via MFMA with V staged transposed.
// key valid iff kg <= qg && kg < vl (key 0 always valid -> no NaN path).
// ---------------------------------------------------------------------------
__global__ __launch_bounds__(256)
void attn_mfma(const unsigned short* __restrict__ qkv,
               const int* __restrict__ vlen, float* __restrict__ aout)
{
    __shared__ unsigned short Qs[64][72];
    __shared__ unsigned short Ks[64][72];
    __shared__ unsigned short Vt[64][72];     // Vt[dim][key]
    __shared__ unsigned short Ps[4][16][72];  // per-wave P (row=q, col=key)

    const int qt  = blockIdx.x;            // 0..31
    const int bh  = blockIdx.y;            // 0..31
    const int b   = bh >> 4;
    const int h   = bh & 15;
    const int q0  = qt * 64;
    const int vl  = vlen[b];
    const int tid = threadIdx.x;
    const int w    = tid >> 6;
    const int lane = tid & 63;
    const int lo   = lane & 15;            // fragment col lane
    const int g    = lane >> 4;            // 16-lane group 0..3
    const int kgrp = g * 8;                // k-offset of this lane's 8 elems

    const unsigned short* qbase = qkv + (size_t)(b * SS) * 3072 + h * 64;
    const unsigned short* kbase = qbase + 1024;
    const unsigned short* vbase = qbase + 2048;

    // stage Q tile (64 x 64 bf16)
#pragma unroll
    for (int u = 0; u < 2; ++u) {
        const int f = tid + u * 256;       // 0..511
        const int r = f >> 3, c8 = (f & 7) * 8;
        *(int4*)&Qs[r][c8] = *(const int4*)(qbase + (size_t)(q0 + r) * 3072 + c8);
    }

    float m[4], l[4];
    f32x4 of[4];
#pragma unroll
    for (int r = 0; r < 4; ++r) { m[r] = -INFINITY; l[r] = 0.f; of[r] = (f32x4)0.f; }

    const int kmax   = min(q0 + 64, vl);
    const int ntiles = (kmax + 63) >> 6;   // >= 1; k0 <= q0 always

    for (int kt = 0; kt < ntiles; ++kt) {
        const int k0 = kt * 64;
        __syncthreads();                   // prev tile fully consumed (and Q staged)
        // stage K rows
#pragma unroll
        for (int u = 0; u < 2; ++u) {
            const int f = tid + u * 256;
            const int r = f >> 3, c8 = (f & 7) * 8;
            *(int4*)&Ks[r][c8] = *(const int4*)(kbase + (size_t)(k0 + r) * 3072 + c8);
        }
        // stage V transposed: Vt[dim][key]
#pragma unroll
        for (int u = 0; u < 2; ++u) {
            const int f = tid + u * 256;
            const int j = f & 63, d0 = (f >> 6) * 8;
            const int4 vv = *(const int4*)(vbase + (size_t)(k0 + j) * 3072 + d0);
            const unsigned short* pv = (const unsigned short*)&vv;
#pragma unroll
            for (int i = 0; i < 8; ++i) Vt[d0 + i][j] = pv[i];
        }
        __syncthreads();

        // S = Q K^T for this wave's 16-row strip (4 col-frags x 2 k-halves)
        f32x4 sf[4];
#pragma unroll
        for (int f = 0; f < 4; ++f) sf[f] = (f32x4)0.f;
        const bf16x8 a0 = *(const bf16x8*)&Qs[w * 16 + lo][kgrp];
        const bf16x8 a1 = *(const bf16x8*)&Qs[w * 16 + lo][32 + kgrp];
#pragma unroll
        for (int f = 0; f < 4; ++f) {
            const bf16x8 b0 = *(const bf16x8*)&Ks[f * 16 + lo][kgrp];
            const bf16x8 b1 = *(const bf16x8*)&Ks[f * 16 + lo][32 + kgrp];
            sf[f] = __builtin_amdgcn_mfma_f32_16x16x32_bf16(a0, b0, sf[f], 0, 0, 0);
            sf[f] = __builtin_amdgcn_mfma_f32_16x16x32_bf16(a1, b1, sf[f], 0, 0, 0);
        }

        // online softmax (rows distributed: row = g*4 + r)
#pragma unroll
        for (int r = 0; r < 4; ++r) {
            const int qg = q0 + w * 16 + g * 4 + r;
            float sv[4];
            float t = -INFINITY;
#pragma unroll
            for (int f = 0; f < 4; ++f) {
                const int kg = k0 + f * 16 + lo;
                const float x = (kg <= qg && kg < vl) ? sf[f][r] * 0.125f : -INFINITY;
                sv[f] = x;
                t = fmaxf(t, x);
            }
#pragma unroll
            for (int off = 1; off < 16; off <<= 1) t = fmaxf(t, __shfl_xor(t, off));
            const float mn   = fmaxf(m[r], t);
            const float corr = __expf(m[r] - mn);
            float ps = 0.f;
#pragma unroll
            for (int f = 0; f < 4; ++f) {
                const float p = __expf(sv[f] - mn);
                ps += p;
                Ps[w][g * 4 + r][f * 16 + lo] = f2bf(p);
            }
#pragma unroll
            for (int off = 1; off < 16; off <<= 1) ps += __shfl_xor(ps, off);
            l[r] = l[r] * corr + ps;
            m[r] = mn;
#pragma unroll
            for (int f = 0; f < 4; ++f) of[f][r] *= corr;
        }
        // per-wave LDS: DS pipe is in-order within a wave; compiler inserts
        // lgkmcnt before the dependent reads below.

        // O += P V   (A = P from Ps, B = V from Vt)
#pragma unroll
        for (int kk = 0; kk < 2; ++kk) {
            const bf16x8 pa = *(const bf16x8*)&Ps[w][lo][kk * 32 + kgrp];
#pragma unroll
            for (int f = 0; f < 4; ++f) {
                const bf16x8 vb = *(const bf16x8*)&Vt[f * 16 + lo][kk * 32 + kgrp];
                of[f] = __builtin_amdgcn_mfma_f32_16x16x32_bf16(pa, vb, of[f], 0, 0, 0);
            }
        }
    }

    // write attention output rows (fp32)
    float* obase = aout + (size_t)(b * SS + q0 + w * 16) * 1024 + h * 64;
#pragma unroll
    for (int f = 0; f < 4; ++f)
#pragma unroll
        for (int r = 0; r < 4; ++r)
            obase[(size_t)(g * 4 + r) * 1024 + f * 16 + lo] = of[f][r] / l[r];
}

extern "C" void kernel_launch(void* const* d_in, const int* in_sizes, int n_in,
                              void* d_out, int out_size, void* d_ws, size_t ws_size,
                              hipStream_t stream) {
    const float* xq = (const float*)d_in[0];
    const float* xk = (const float*)d_in[1];
    const float* xv = (const float*)d_in[2];
    const int*   vl = (const int*)  d_in[3];
    const float* wq = (const float*)d_in[4];
    const float* bq = (const float*)d_in[5];
    const float* wk = (const float*)d_in[6];
    const float* bk = (const float*)d_in[7];
    const float* wv = (const float*)d_in[8];
    const float* bv = (const float*)d_in[9];
    const float* wo = (const float*)d_in[10];
    const float* bo = (const float*)d_in[11];

    unsigned short* qkvbuf = (unsigned short*)d_ws;                 // 4096x3072 bf16
    float* abuf = (float*)((char*)d_ws + (size_t)MROWS * 3072 * 2); // 4096x1024 f32

    qkv_proj<<<dim3(24, 32), 256, 0, stream>>>(xq, xk, xv, wq, bq, wk, bk,
                                               wv, bv, qkvbuf);
    attn_mfma<<<dim3(SS / 64, BB * NH), 256, 0, stream>>>(qkvbuf, vl, abuf);
    out_proj<<<dim3(8, 32), 256, 0, stream>>>(abuf, wo, bo, (float*)d_out);
}

// Round 3
// 175.962 us; speedup vs baseline: 9.7346x; 3.4631x over previous
//
#include <hip/hip_runtime.h>
#include <math.h>

#define NH 16
#define HD 64
#define DM 1024
#define BB 2
#define SS 2048
#define MROWS (BB*SS)   // 4096
#define MEG 1048576

typedef __attribute__((ext_vector_type(8))) short bf16x8;
typedef __attribute__((ext_vector_type(4))) float f32x4;

__device__ __forceinline__ unsigned short f2bf(float x) {
    unsigned int u = __float_as_uint(x);
    u += 0x7fff + ((u >> 16) & 1);          // round-to-nearest-even
    return (unsigned short)(u >> 16);
}

#define GLD_LDS16(gp, lp) __builtin_amdgcn_global_load_lds(                  \
        (const __attribute__((address_space(1))) void*)(gp),                 \
        (__attribute__((address_space(3))) void*)(lp), 16, 0, 0)

// ---------------------------------------------------------------------------
// fp32 -> bf16 conversion for the 3 inputs and 4 weight matrices.
// ws layout (elements of bf16):
//   0       : xqb (4M)    4M: xkb    8M: xvb
//   12M     : wqb (1M)   13M: wkb   14M: wvb   15M: wob
//   16M     : qkvbuf (12M)          28M: abuf (4M)
// ---------------------------------------------------------------------------
__global__ __launch_bounds__(256)
void cvt_all(const float* __restrict__ xq, const float* __restrict__ xk,
             const float* __restrict__ xv, const float* __restrict__ wq,
             const float* __restrict__ wk, const float* __restrict__ wv,
             const float* __restrict__ wo, unsigned short* __restrict__ ws)
{
    const int reg = blockIdx.y;                       // 0..6
    const size_t n    = (reg < 3) ? (size_t)4 * MEG : (size_t)MEG;
    const size_t roff = (reg < 3) ? (size_t)reg * 4 * MEG
                                  : (size_t)12 * MEG + (size_t)(reg - 3) * MEG;
    const float* src = (reg == 0) ? xq : (reg == 1) ? xk : (reg == 2) ? xv :
                       (reg == 3) ? wq : (reg == 4) ? wk : (reg == 5) ? wv : wo;
    const size_t i = ((size_t)blockIdx.x * 256 + threadIdx.x) * 8;
    if (i >= n) return;
    const float4 a = *(const float4*)(src + i);
    const float4 b = *(const float4*)(src + i + 4);
    ushort4 lo4, hi4;
    lo4.x = f2bf(a.x); lo4.y = f2bf(a.y); lo4.z = f2bf(a.z); lo4.w = f2bf(a.w);
    hi4.x = f2bf(b.x); hi4.y = f2bf(b.y); hi4.z = f2bf(b.z); hi4.w = f2bf(b.w);
    *(ushort4*)(ws + roff + i)     = lo4;
    *(ushort4*)(ws + roff + i + 4) = hi4;
}

// ---------------------------------------------------------------------------
// bf16 MFMA GEMM (m97 structure): Y[m][n] = sum_k A[m][k]*W[n][k] + bias[n]
// 128x128 tile, BK=64, 256 threads = 4 waves in 2x2; each wave: 64x64 out
// (4x4 fragments of 16x16x32). global_load_lds 16B staging, linear LDS.
// ---------------------------------------------------------------------------
template<bool BF16OUT>
__device__ __forceinline__ void gemm_mfma_core(
    const unsigned short* __restrict__ A, int lda,
    const unsigned short* __restrict__ W, int ldw,
    const float* __restrict__ bias,
    void* __restrict__ Y, int ldy)
{
    __shared__ unsigned short As[128 * 64];
    __shared__ unsigned short Bs[128 * 64];

    const int tid  = threadIdx.x;
    const int w    = tid >> 6;
    const int lane = tid & 63;
    const int lo   = lane & 15;
    const int g    = lane >> 4;
    const int wr   = (w >> 1) * 64;
    const int wc   = (w & 1) * 64;

    f32x4 acc[4][4];
#pragma unroll
    for (int i = 0; i < 4; ++i)
#pragma unroll
        for (int j = 0; j < 4; ++j) acc[i][j] = (f32x4)0.f;

    for (int k0 = 0; k0 < 1024; k0 += 64) {
        __syncthreads();                       // prev tile fully consumed
#pragma unroll
        for (int u = 0; u < 4; ++u) {
            const int e   = (u * 256 + tid) * 8;   // bf16 element index in tile
            const int row = e >> 6, col = e & 63;
            GLD_LDS16(A + (size_t)row * lda + k0 + col, As + e);
            GLD_LDS16(W + (size_t)row * ldw + k0 + col, Bs + e);
        }
        asm volatile("s_waitcnt vmcnt(0)" ::: "memory");
        __syncthreads();

#pragma unroll
        for (int kk = 0; kk < 2; ++kk) {
            bf16x8 af[4], bf[4];
#pragma unroll
            for (int i = 0; i < 4; ++i) {
                af[i] = *(const bf16x8*)(As + (wr + i * 16 + lo) * 64 + kk * 32 + g * 8);
                bf[i] = *(const bf16x8*)(Bs + (wc + i * 16 + lo) * 64 + kk * 32 + g * 8);
            }
#pragma unroll
            for (int i = 0; i < 4; ++i)
#pragma unroll
                for (int j = 0; j < 4; ++j)
                    acc[i][j] = __builtin_amdgcn_mfma_f32_16x16x32_bf16(
                        af[i], bf[j], acc[i][j], 0, 0, 0);
        }
    }

    // epilogue: C row = g*4 + r, col = lo (within each 16x16 fragment)
#pragma unroll
    for (int i = 0; i < 4; ++i) {
        const int row = wr + i * 16 + g * 4;
#pragma unroll
        for (int j = 0; j < 4; ++j) {
            const int col = wc + j * 16 + lo;
            const float bv = bias[col];
#pragma unroll
            for (int r = 0; r < 4; ++r) {
                const float v = acc[i][j][r] + bv;
                if constexpr (BF16OUT)
                    ((unsigned short*)Y)[(size_t)(row + r) * ldy + col] = f2bf(v);
                else
                    ((float*)Y)[(size_t)(row + r) * ldy + col] = v;
            }
        }
    }
}

// QKV projection -> bf16 qkvbuf (4096 x 3072)
__global__ __launch_bounds__(256)
void qkv_proj(const unsigned short* __restrict__ ws,
              const float* __restrict__ bq, const float* __restrict__ bk,
              const float* __restrict__ bv, unsigned short* __restrict__ Y)
{
    const int nblk = blockIdx.x;            // 0..23
    const int m0   = blockIdx.y * 128;
    const int mat  = nblk >> 3;
    const int ncol = (nblk & 7) * 128;
    const unsigned short* A = ws + (size_t)mat * 4 * MEG + (size_t)m0 * 1024;
    const unsigned short* W = ws + (size_t)12 * MEG + (size_t)mat * MEG
                                 + (size_t)ncol * 1024;
    const float* bias = ((mat == 0) ? bq : (mat == 1) ? bk : bv) + ncol;
    gemm_mfma_core<true>(A, 1024, W, 1024, bias,
                         Y + (size_t)m0 * 3072 + nblk * 128, 3072);
}

// Output projection: d_out (4096 x 1024 fp32) = abuf @ wo^T + bo
__global__ __launch_bounds__(256)
void out_proj(const unsigned short* __restrict__ ws,
              const float* __restrict__ bo, float* __restrict__ out)
{
    const int n0 = blockIdx.x * 128;
    const int m0 = blockIdx.y * 128;
    const unsigned short* A = ws + (size_t)28 * MEG + (size_t)m0 * 1024;
    const unsigned short* W = ws + (size_t)15 * MEG + (size_t)n0 * 1024;
    gemm_mfma_core<false>(A, 1024, W, 1024, bo + n0,
                          out + (size_t)m0 * 1024 + n0, 1024);
}

// ---------------------------------------------------------------------------
// MFMA flash attention (unchanged structure from round 1; bf16 output now).
// ---------------------------------------------------------------------------
__global__ __launch_bounds__(256)
void attn_mfma(const unsigned short* __restrict__ qkv,
               const int* __restrict__ vlen, unsigned short* __restrict__ aout)
{
    __shared__ unsigned short Qs[64][72];
    __shared__ unsigned short Ks[64][72];
    __shared__ unsigned short Vt[64][72];     // Vt[dim][key]
    __shared__ unsigned short Ps[4][16][72];  // per-wave P (row=q, col=key)

    const int qt  = blockIdx.x;
    const int bh  = blockIdx.y;
    const int b   = bh >> 4;
    const int h   = bh & 15;
    const int q0  = qt * 64;
    const int vl  = vlen[b];
    const int tid = threadIdx.x;
    const int w    = tid >> 6;
    const int lane = tid & 63;
    const int lo   = lane & 15;
    const int g    = lane >> 4;
    const int kgrp = g * 8;

    const unsigned short* qbase = qkv + (size_t)(b * SS) * 3072 + h * 64;
    const unsigned short* kbase = qbase + 1024;
    const unsigned short* vbase = qbase + 2048;

#pragma unroll
    for (int u = 0; u < 2; ++u) {
        const int f = tid + u * 256;
        const int r = f >> 3, c8 = (f & 7) * 8;
        *(int4*)&Qs[r][c8] = *(const int4*)(qbase + (size_t)(q0 + r) * 3072 + c8);
    }

    float m[4], l[4];
    f32x4 of[4];
#pragma unroll
    for (int r = 0; r < 4; ++r) { m[r] = -INFINITY; l[r] = 0.f; of[r] = (f32x4)0.f; }

    const int kmax   = min(q0 + 64, vl);
    const int ntiles = (kmax + 63) >> 6;

    for (int kt = 0; kt < ntiles; ++kt) {
        const int k0 = kt * 64;
        __syncthreads();
#pragma unroll
        for (int u = 0; u < 2; ++u) {
            const int f = tid + u * 256;
            const int r = f >> 3, c8 = (f & 7) * 8;
            *(int4*)&Ks[r][c8] = *(const int4*)(kbase + (size_t)(k0 + r) * 3072 + c8);
        }
#pragma unroll
        for (int u = 0; u < 2; ++u) {
            const int f = tid + u * 256;
            const int j = f & 63, d0 = (f >> 6) * 8;
            const int4 vv = *(const int4*)(vbase + (size_t)(k0 + j) * 3072 + d0);
            const unsigned short* pv = (const unsigned short*)&vv;
#pragma unroll
            for (int i = 0; i < 8; ++i) Vt[d0 + i][j] = pv[i];
        }
        __syncthreads();

        f32x4 sf[4];
#pragma unroll
        for (int f = 0; f < 4; ++f) sf[f] = (f32x4)0.f;
        const bf16x8 a0 = *(const bf16x8*)&Qs[w * 16 + lo][kgrp];
        const bf16x8 a1 = *(const bf16x8*)&Qs[w * 16 + lo][32 + kgrp];
#pragma unroll
        for (int f = 0; f < 4; ++f) {
            const bf16x8 b0 = *(const bf16x8*)&Ks[f * 16 + lo][kgrp];
            const bf16x8 b1 = *(const bf16x8*)&Ks[f * 16 + lo][32 + kgrp];
            sf[f] = __builtin_amdgcn_mfma_f32_16x16x32_bf16(a0, b0, sf[f], 0, 0, 0);
            sf[f] = __builtin_amdgcn_mfma_f32_16x16x32_bf16(a1, b1, sf[f], 0, 0, 0);
        }

#pragma unroll
        for (int r = 0; r < 4; ++r) {
            const int qg = q0 + w * 16 + g * 4 + r;
            float sv[4];
            float t = -INFINITY;
#pragma unroll
            for (int f = 0; f < 4; ++f) {
                const int kg = k0 + f * 16 + lo;
                const float x = (kg <= qg && kg < vl) ? sf[f][r] * 0.125f : -INFINITY;
                sv[f] = x;
                t = fmaxf(t, x);
            }
#pragma unroll
            for (int off = 1; off < 16; off <<= 1) t = fmaxf(t, __shfl_xor(t, off));
            const float mn   = fmaxf(m[r], t);
            const float corr = __expf(m[r] - mn);
            float ps = 0.f;
#pragma unroll
            for (int f = 0; f < 4; ++f) {
                const float p = __expf(sv[f] - mn);
                ps += p;
                Ps[w][g * 4 + r][f * 16 + lo] = f2bf(p);
            }
#pragma unroll
            for (int off = 1; off < 16; off <<= 1) ps += __shfl_xor(ps, off);
            l[r] = l[r] * corr + ps;
            m[r] = mn;
#pragma unroll
            for (int f = 0; f < 4; ++f) of[f][r] *= corr;
        }

#pragma unroll
        for (int kk = 0; kk < 2; ++kk) {
            const bf16x8 pa = *(const bf16x8*)&Ps[w][lo][kk * 32 + kgrp];
#pragma unroll
            for (int f = 0; f < 4; ++f) {
                const bf16x8 vb = *(const bf16x8*)&Vt[f * 16 + lo][kk * 32 + kgrp];
                of[f] = __builtin_amdgcn_mfma_f32_16x16x32_bf16(pa, vb, of[f], 0, 0, 0);
            }
        }
    }

    unsigned short* obase = aout + (size_t)(b * SS + q0 + w * 16) * 1024 + h * 64;
#pragma unroll
    for (int r = 0; r < 4; ++r) {
        const float rinv = 1.0f / l[r];
#pragma unroll
        for (int f = 0; f < 4; ++f)
            obase[(size_t)(g * 4 + r) * 1024 + f * 16 + lo] = f2bf(of[f][r] * rinv);
    }
}

extern "C" void kernel_launch(void* const* d_in, const int* in_sizes, int n_in,
                              void* d_out, int out_size, void* d_ws, size_t ws_size,
                              hipStream_t stream) {
    const float* xq = (const float*)d_in[0];
    const float* xk = (const float*)d_in[1];
    const float* xv = (const float*)d_in[2];
    const int*   vl = (const int*)  d_in[3];
    const float* bq = (const float*)d_in[5];
    const float* bk = (const float*)d_in[7];
    const float* bv = (const float*)d_in[9];
    const float* wo = (const float*)d_in[10];
    const float* bo = (const float*)d_in[11];
    const float* wq = (const float*)d_in[4];
    const float* wk = (const float*)d_in[6];
    const float* wv = (const float*)d_in[8];

    unsigned short* ws = (unsigned short*)d_ws;
    unsigned short* qkvbuf = ws + (size_t)16 * MEG;   // 4096x3072 bf16
    unsigned short* abuf   = ws + (size_t)28 * MEG;   // 4096x1024 bf16

    cvt_all<<<dim3(2048, 7), 256, 0, stream>>>(xq, xk, xv, wq, wk, wv, wo, ws);
    qkv_proj<<<dim3(24, 32), 256, 0, stream>>>(ws, bq, bk, bv, qkvbuf);
    attn_mfma<<<dim3(SS / 64, BB * NH), 256, 0, stream>>>(qkvbuf, vl, abuf);
    out_proj<<<dim3(8, 32), 256, 0, stream>>>(ws, bo, (float*)d_out);
}

// Round 4
// 164.676 us; speedup vs baseline: 10.4018x; 1.0685x over previous
//
#include <hip/hip_runtime.h>
#include <math.h>

#define NH 16
#define HD 64
#define DM 1024
#define BB 2
#define SS 2048
#define MROWS (BB*SS)   // 4096
#define MEG 1048576

typedef __attribute__((ext_vector_type(8))) short bf16x8;
typedef __attribute__((ext_vector_type(4))) float f32x4;

__device__ __forceinline__ unsigned short f2bf(float x) {
    unsigned int u = __float_as_uint(x);
    u += 0x7fff + ((u >> 16) & 1);          // round-to-nearest-even
    return (unsigned short)(u >> 16);
}

#define GLD_LDS16(gp, lp) __builtin_amdgcn_global_load_lds(                  \
        (const __attribute__((address_space(1))) void*)(gp),                 \
        (__attribute__((address_space(3))) void*)(lp), 16, 0, 0)

// ---------------------------------------------------------------------------
// ws layout (bf16 elements):
//   0   : xqb (4M)   4M: xkb   8M: xvb
//   12M : wqb (1M)  13M: wkb  14M: wvb  15M: wob
//   16M : qkbuf (8M)  [4096][2048]  (Q cols 0..1023, K cols 1024..2047)
//   24M : VT (4M)     [2][1024][2048]  V^T per batch, token-chunk swizzled
//   28M : abuf (4M)   [4096][1024]
// ---------------------------------------------------------------------------
__global__ __launch_bounds__(256)
void cvt_all(const float* __restrict__ xq, const float* __restrict__ xk,
             const float* __restrict__ xv, const float* __restrict__ wq,
             const float* __restrict__ wk, const float* __restrict__ wv,
             const float* __restrict__ wo, unsigned short* __restrict__ ws)
{
    const int reg = blockIdx.y;                       // 0..6
    const size_t n    = (reg < 3) ? (size_t)4 * MEG : (size_t)MEG;
    const size_t roff = (reg < 3) ? (size_t)reg * 4 * MEG
                                  : (size_t)12 * MEG + (size_t)(reg - 3) * MEG;
    const float* src = (reg == 0) ? xq : (reg == 1) ? xk : (reg == 2) ? xv :
                       (reg == 3) ? wq : (reg == 4) ? wk : (reg == 5) ? wv : wo;
    const size_t i = ((size_t)blockIdx.x * 256 + threadIdx.x) * 8;
    if (i >= n) return;
    const float4 a = *(const float4*)(src + i);
    const float4 b = *(const float4*)(src + i + 4);
    ushort4 lo4, hi4;
    lo4.x = f2bf(a.x); lo4.y = f2bf(a.y); lo4.z = f2bf(a.z); lo4.w = f2bf(a.w);
    hi4.x = f2bf(b.x); hi4.y = f2bf(b.y); hi4.z = f2bf(b.z); hi4.w = f2bf(b.w);
    *(ushort4*)(ws + roff + i)     = lo4;
    *(ushort4*)(ws + roff + i + 4) = hi4;
}

// ---------------------------------------------------------------------------
// bf16 MFMA GEMM (m97 structure): D[m][n] = sum_k A[m][k]*W[n][k] (+bias)
// 128x128 tile, BK=64, 4 waves in 2x2, each 64x64 out (4x4 frags 16x16x32).
// MODE 0: bf16 out, col-bias.  MODE 1: f32 out, col-bias.
// MODE 2: bf16 out, ROW-bias, token-chunk XOR swizzle on col (V^T producer).
// ---------------------------------------------------------------------------
template<int MODE>
__device__ __forceinline__ void gemm_mfma_core(
    const unsigned short* __restrict__ A,
    const unsigned short* __restrict__ W,
    const float* __restrict__ bias,
    void* __restrict__ Y, int ldy)
{
    __shared__ unsigned short As[128 * 64];
    __shared__ unsigned short Bs[128 * 64];

    const int tid  = threadIdx.x;
    const int w    = tid >> 6;
    const int lane = tid & 63;
    const int lo   = lane & 15;
    const int g    = lane >> 4;
    const int wr   = (w >> 1) * 64;
    const int wc   = (w & 1) * 64;

    f32x4 acc[4][4];
#pragma unroll
    for (int i = 0; i < 4; ++i)
#pragma unroll
        for (int j = 0; j < 4; ++j) acc[i][j] = (f32x4)0.f;

    for (int k0 = 0; k0 < 1024; k0 += 64) {
        __syncthreads();
#pragma unroll
        for (int u = 0; u < 4; ++u) {
            const int e   = (u * 256 + tid) * 8;
            const int row = e >> 6, col = e & 63;
            GLD_LDS16(A + (size_t)row * 1024 + k0 + col, As + e);
            GLD_LDS16(W + (size_t)row * 1024 + k0 + col, Bs + e);
        }
        asm volatile("s_waitcnt vmcnt(0)" ::: "memory");
        __syncthreads();

#pragma unroll
        for (int kk = 0; kk < 2; ++kk) {
            bf16x8 af[4], bf[4];
#pragma unroll
            for (int i = 0; i < 4; ++i) {
                af[i] = *(const bf16x8*)(As + (wr + i * 16 + lo) * 64 + kk * 32 + g * 8);
                bf[i] = *(const bf16x8*)(Bs + (wc + i * 16 + lo) * 64 + kk * 32 + g * 8);
            }
#pragma unroll
            for (int i = 0; i < 4; ++i)
#pragma unroll
                for (int j = 0; j < 4; ++j)
                    acc[i][j] = __builtin_amdgcn_mfma_f32_16x16x32_bf16(
                        af[i], bf[j], acc[i][j], 0, 0, 0);
        }
    }

#pragma unroll
    for (int i = 0; i < 4; ++i) {
#pragma unroll
        for (int j = 0; j < 4; ++j) {
            const int col = wc + j * 16 + lo;
#pragma unroll
            for (int r = 0; r < 4; ++r) {
                const int row = wr + i * 16 + g * 4 + r;
                if constexpr (MODE == 2) {
                    const float v = acc[i][j][r] + bias[row];
                    const int jc = (col & ~63) | ((((col >> 3) & 7) ^ (row & 7)) << 3)
                                 | (col & 7);
                    ((unsigned short*)Y)[(size_t)row * ldy + jc] = f2bf(v);
                } else {
                    const float v = acc[i][j][r] + bias[col];
                    if constexpr (MODE == 0)
                        ((unsigned short*)Y)[(size_t)row * ldy + col] = f2bf(v);
                    else
                        ((float*)Y)[(size_t)row * ldy + col] = v;
                }
            }
        }
    }
}

// grid (24, 32): nblk<16 -> Q/K into qkbuf; nblk>=16 -> V^T GEMM into VT.
__global__ __launch_bounds__(256)
void qkv_proj(const unsigned short* __restrict__ ws,
              const float* __restrict__ bq, const float* __restrict__ bk,
              const float* __restrict__ bv,
              unsigned short* __restrict__ qk, unsigned short* __restrict__ vt)
{
    const int nblk = blockIdx.x;
    if (nblk < 16) {
        const int mat  = nblk >> 3;                 // 0=Q 1=K
        const int ncol = (nblk & 7) * 128;
        const int m0   = blockIdx.y * 128;
        const unsigned short* A = ws + (size_t)mat * 4 * MEG + (size_t)m0 * 1024;
        const unsigned short* W = ws + (size_t)12 * MEG + (size_t)mat * MEG
                                     + (size_t)ncol * 1024;
        const float* bias = ((mat == 0) ? bq : bk) + ncol;
        gemm_mfma_core<0>(A, W, bias,
                          qk + (size_t)m0 * 2048 + mat * 1024 + ncol, 2048);
    } else {
        // V^T[b] = w_v @ x_v[b]^T : A = w_v rows(dims), W = x_v[b] rows(tokens)
        const int rowblk = nblk - 16;               // 0..7 (dim block)
        const int b      = blockIdx.y >> 4;
        const int colblk = blockIdx.y & 15;         // token block
        const unsigned short* A = ws + (size_t)14 * MEG + (size_t)rowblk * 128 * 1024;
        const unsigned short* W = ws + (size_t)8 * MEG + (size_t)b * 2 * MEG
                                     + (size_t)colblk * 128 * 1024;
        gemm_mfma_core<2>(A, W, bv + rowblk * 128,
                          vt + (size_t)b * 1024 * 2048
                             + (size_t)rowblk * 128 * 2048 + colblk * 128, 2048);
    }
}

__global__ __launch_bounds__(256)
void out_proj(const unsigned short* __restrict__ ws,
              const float* __restrict__ bo, float* __restrict__ out)
{
    const int n0 = blockIdx.x * 128;
    const int m0 = blockIdx.y * 128;
    const unsigned short* A = ws + (size_t)28 * MEG + (size_t)m0 * 1024;
    const unsigned short* W = ws + (size_t)15 * MEG + (size_t)n0 * 1024;
    gemm_mfma_core<1>(A, W, bo + n0, out + (size_t)m0 * 1024 + n0, 1024);
}

// ---------------------------------------------------------------------------
// MFMA flash attention v2: grid (bh=32, qt=32) for CU load balance.
// Q in registers; K gathered via global_load_lds with pre-swizzled source;
// V^T staged linear from the pre-swizzled VT buffer. Fragment reads apply
// chunk ^= (row&7) -> <=2-way banks. LDS 25.6KB -> 6 blocks/CU.
// ---------------------------------------------------------------------------
__global__ __launch_bounds__(256)
void attn_mfma(const unsigned short* __restrict__ qk,
               const unsigned short* __restrict__ vt,
               const int* __restrict__ vlen, unsigned short* __restrict__ aout)
{
    __shared__ unsigned short Ks[64 * 64];
    __shared__ unsigned short Vs[64 * 64];
    __shared__ unsigned short Ps[4][16][72];

    const int bh  = blockIdx.x;
    const int qt  = blockIdx.y;
    const int b   = bh >> 4;
    const int h   = bh & 15;
    const int q0  = qt * 64;
    const int vl  = vlen[b];
    const int tid = threadIdx.x;
    const int w    = tid >> 6;
    const int lane = tid & 63;
    const int lo   = lane & 15;
    const int g    = lane >> 4;

    const unsigned short* qbase = qk + (size_t)(b * SS) * 2048 + h * 64;
    const unsigned short* kbase = qbase + 1024;
    const unsigned short* vtb   = vt + (size_t)b * 1024 * 2048
                                     + (size_t)(h * 64) * 2048;

    // Q fragment straight to registers (A-frag rows = lo)
    const int qrow = q0 + w * 16 + lo;
    const bf16x8 a0 = *(const bf16x8*)(qbase + (size_t)qrow * 2048 + g * 8);
    const bf16x8 a1 = *(const bf16x8*)(qbase + (size_t)qrow * 2048 + 32 + g * 8);

    float m[4], l[4];
    f32x4 of[4];
#pragma unroll
    for (int r = 0; r < 4; ++r) { m[r] = -INFINITY; l[r] = 0.f; of[r] = (f32x4)0.f; }

    const int kmax   = min(q0 + 64, vl);
    const int ntiles = (kmax + 63) >> 6;

    for (int kt = 0; kt < ntiles; ++kt) {
        const int k0 = kt * 64;
        __syncthreads();                       // prev tile fully consumed
        // stage K (swizzled gather) and V^T (linear; swizzle baked in VT)
#pragma unroll
        for (int u = 0; u < 2; ++u) {
            const int e = w * 128 + u * 64 + lane;   // 16B chunk index 0..511
            const int r = e >> 3, c = e & 7;
            GLD_LDS16(kbase + (size_t)(k0 + r) * 2048 + ((c ^ (r & 7)) * 8),
                      Ks + e * 8);
            GLD_LDS16(vtb + (size_t)r * 2048 + k0 + c * 8, Vs + e * 8);
        }
        asm volatile("s_waitcnt vmcnt(0)" ::: "memory");
        __syncthreads();

        // S = Q K^T (16-row strip per wave)
        f32x4 sf[4];
#pragma unroll
        for (int f = 0; f < 4; ++f) sf[f] = (f32x4)0.f;
#pragma unroll
        for (int f = 0; f < 4; ++f) {
            const int kr = f * 16 + lo;
            const bf16x8 b0 = *(const bf16x8*)(Ks + kr * 64 + ((g ^ (lo & 7)) * 8));
            const bf16x8 b1 = *(const bf16x8*)(Ks + kr * 64 + (((4 + g) ^ (lo & 7)) * 8));
            sf[f] = __builtin_amdgcn_mfma_f32_16x16x32_bf16(a0, b0, sf[f], 0, 0, 0);
            sf[f] = __builtin_amdgcn_mfma_f32_16x16x32_bf16(a1, b1, sf[f], 0, 0, 0);
        }

        // online softmax (C-layout: col=lo=key, row=g*4+r)
#pragma unroll
        for (int r = 0; r < 4; ++r) {
            const int qg = q0 + w * 16 + g * 4 + r;
            float sv[4];
            float t = -INFINITY;
#pragma unroll
            for (int f = 0; f < 4; ++f) {
                const int kg = k0 + f * 16 + lo;
                const float x = (kg <= qg && kg < vl) ? sf[f][r] * 0.125f : -INFINITY;
                sv[f] = x;
                t = fmaxf(t, x);
            }
#pragma unroll
            for (int off = 1; off < 16; off <<= 1) t = fmaxf(t, __shfl_xor(t, off));
            const float mn   = fmaxf(m[r], t);
            const float corr = __expf(m[r] - mn);
            float ps = 0.f;
#pragma unroll
            for (int f = 0; f < 4; ++f) {
                const float p = __expf(sv[f] - mn);
                ps += p;
                Ps[w][g * 4 + r][f * 16 + lo] = f2bf(p);
            }
#pragma unroll
            for (int off = 1; off < 16; off <<= 1) ps += __shfl_xor(ps, off);
            l[r] = l[r] * corr + ps;
            m[r] = mn;
#pragma unroll
            for (int f = 0; f < 4; ++f) of[f][r] *= corr;
        }

        // O += P V  (pa: rows=lo of P; vb: V^T rows = dims, swizzled chunks)
#pragma unroll
        for (int kk = 0; kk < 2; ++kk) {
            const bf16x8 pa = *(const bf16x8*)&Ps[w][lo][kk * 32 + g * 8];
#pragma unroll
            for (int f = 0; f < 4; ++f) {
                const int dr = f * 16 + lo;
                const bf16x8 vb = *(const bf16x8*)(Vs + dr * 64
                                    + (((4 * kk + g) ^ (lo & 7)) * 8));
                of[f] = __builtin_amdgcn_mfma_f32_16x16x32_bf16(pa, vb, of[f], 0, 0, 0);
            }
        }
    }

    unsigned short* obase = aout + (size_t)(b * SS + q0 + w * 16) * 1024 + h * 64;
#pragma unroll
    for (int r = 0; r < 4; ++r) {
        const float rinv = 1.0f / l[r];
#pragma unroll
        for (int f = 0; f < 4; ++f)
            obase[(size_t)(g * 4 + r) * 1024 + f * 16 + lo] = f2bf(of[f][r] * rinv);
    }
}

extern "C" void kernel_launch(void* const* d_in, const int* in_sizes, int n_in,
                              void* d_out, int out_size, void* d_ws, size_t ws_size,
                              hipStream_t stream) {
    const float* xq = (const float*)d_in[0];
    const float* xk = (const float*)d_in[1];
    const float* xv = (const float*)d_in[2];
    const int*   vl = (const int*)  d_in[3];
    const float* wq = (const float*)d_in[4];
    const float* bq = (const float*)d_in[5];
    const float* wk = (const float*)d_in[6];
    const float* bk = (const float*)d_in[7];
    const float* wv = (const float*)d_in[8];
    const float* bv = (const float*)d_in[9];
    const float* wo = (const float*)d_in[10];
    const float* bo = (const float*)d_in[11];

    unsigned short* ws     = (unsigned short*)d_ws;
    unsigned short* qkbuf  = ws + (size_t)16 * MEG;
    unsigned short* vtbuf  = ws + (size_t)24 * MEG;
    unsigned short* abuf   = ws + (size_t)28 * MEG;

    cvt_all<<<dim3(2048, 7), 256, 0, stream>>>(xq, xk, xv, wq, wk, wv, wo, ws);
    qkv_proj<<<dim3(24, 32), 256, 0, stream>>>(ws, bq, bk, bv, qkbuf, vtbuf);
    attn_mfma<<<dim3(BB * NH, SS / 64), 256, 0, stream>>>(qkbuf, vtbuf, vl,
                                                          abuf);
    out_proj<<<dim3(8, 32), 256, 0, stream>>>(ws, bo, (float*)d_out);
}

// Round 5
// 150.582 us; speedup vs baseline: 11.3754x; 1.0936x over previous
//
#include <hip/hip_runtime.h>
#include <math.h>

#define NH 16
#define HD 64
#define DM 1024
#define BB 2
#define SS 2048
#define MROWS (BB*SS)   // 4096
#define MEG 1048576

typedef __attribute__((ext_vector_type(8))) short bf16x8;
typedef __attribute__((ext_vector_type(4))) float f32x4;

__device__ __forceinline__ unsigned short f2bf(float x) {
    unsigned int u = __float_as_uint(x);
    u += 0x7fff + ((u >> 16) & 1);          // round-to-nearest-even
    return (unsigned short)(u >> 16);
}

#define GLD_LDS16(gp, lp) __builtin_amdgcn_global_load_lds(                  \
        (const __attribute__((address_space(1))) void*)(gp),                 \
        (__attribute__((address_space(3))) void*)(lp), 16, 0, 0)

// ---------------------------------------------------------------------------
// ws layout (bf16 elements):
//   0   : xqb (4M)   4M: xkb   8M: xvb
//   12M : wqb (1M)  13M: wkb  14M: wvb  15M: wob
//   16M : qkbuf (8M)  [4096][2048]  (Q cols 0..1023, K cols 1024..2047)
//   24M : VT (4M)     [2][1024][2048]  V^T per batch, token-chunk swizzled
//   28M : abuf (4M)   [4096][1024]
// ---------------------------------------------------------------------------
__global__ __launch_bounds__(256)
void cvt_all(const float* __restrict__ xq, const float* __restrict__ xk,
             const float* __restrict__ xv, const float* __restrict__ wq,
             const float* __restrict__ wk, const float* __restrict__ wv,
             const float* __restrict__ wo, unsigned short* __restrict__ ws)
{
    const int reg = blockIdx.y;                       // 0..6
    const size_t n    = (reg < 3) ? (size_t)4 * MEG : (size_t)MEG;
    const size_t roff = (reg < 3) ? (size_t)reg * 4 * MEG
                                  : (size_t)12 * MEG + (size_t)(reg - 3) * MEG;
    const float* src = (reg == 0) ? xq : (reg == 1) ? xk : (reg == 2) ? xv :
                       (reg == 3) ? wq : (reg == 4) ? wk : (reg == 5) ? wv : wo;
    const size_t i = ((size_t)blockIdx.x * 256 + threadIdx.x) * 8;
    if (i >= n) return;
    const float4 a = *(const float4*)(src + i);
    const float4 b = *(const float4*)(src + i + 4);
    ushort4 lo4, hi4;
    lo4.x = f2bf(a.x); lo4.y = f2bf(a.y); lo4.z = f2bf(a.z); lo4.w = f2bf(a.w);
    hi4.x = f2bf(b.x); hi4.y = f2bf(b.y); hi4.z = f2bf(b.z); hi4.w = f2bf(b.w);
    *(ushort4*)(ws + roff + i)     = lo4;
    *(ushort4*)(ws + roff + i + 4) = hi4;
}

// ---------------------------------------------------------------------------
// bf16 MFMA GEMM (m97 structure): D[m][n] = sum_k A[m][k]*W[n][k] (+bias)
// 128x128 tile, BK=64, 4 waves in 2x2, each 64x64 out (4x4 frags 16x16x32).
// MODE 0: bf16 out, col-bias.  MODE 1: f32 out, col-bias.
// MODE 2: bf16 out, ROW-bias, token-chunk XOR swizzle on col (V^T producer).
// ---------------------------------------------------------------------------
template<int MODE>
__device__ __forceinline__ void gemm_mfma_core(
    const unsigned short* __restrict__ A,
    const unsigned short* __restrict__ W,
    const float* __restrict__ bias,
    void* __restrict__ Y, int ldy)
{
    __shared__ unsigned short As[128 * 64];
    __shared__ unsigned short Bs[128 * 64];

    const int tid  = threadIdx.x;
    const int w    = tid >> 6;
    const int lane = tid & 63;
    const int lo   = lane & 15;
    const int g    = lane >> 4;
    const int wr   = (w >> 1) * 64;
    const int wc   = (w & 1) * 64;

    f32x4 acc[4][4];
#pragma unroll
    for (int i = 0; i < 4; ++i)
#pragma unroll
        for (int j = 0; j < 4; ++j) acc[i][j] = (f32x4)0.f;

    for (int k0 = 0; k0 < 1024; k0 += 64) {
        __syncthreads();
#pragma unroll
        for (int u = 0; u < 4; ++u) {
            const int e   = (u * 256 + tid) * 8;
            const int row = e >> 6, col = e & 63;
            GLD_LDS16(A + (size_t)row * 1024 + k0 + col, As + e);
            GLD_LDS16(W + (size_t)row * 1024 + k0 + col, Bs + e);
        }
        asm volatile("s_waitcnt vmcnt(0)" ::: "memory");
        __syncthreads();

#pragma unroll
        for (int kk = 0; kk < 2; ++kk) {
            bf16x8 af[4], bf[4];
#pragma unroll
            for (int i = 0; i < 4; ++i) {
                af[i] = *(const bf16x8*)(As + (wr + i * 16 + lo) * 64 + kk * 32 + g * 8);
                bf[i] = *(const bf16x8*)(Bs + (wc + i * 16 + lo) * 64 + kk * 32 + g * 8);
            }
#pragma unroll
            for (int i = 0; i < 4; ++i)
#pragma unroll
                for (int j = 0; j < 4; ++j)
                    acc[i][j] = __builtin_amdgcn_mfma_f32_16x16x32_bf16(
                        af[i], bf[j], acc[i][j], 0, 0, 0);
        }
    }

#pragma unroll
    for (int i = 0; i < 4; ++i) {
#pragma unroll
        for (int j = 0; j < 4; ++j) {
            const int col = wc + j * 16 + lo;
#pragma unroll
            for (int r = 0; r < 4; ++r) {
                const int row = wr + i * 16 + g * 4 + r;
                if constexpr (MODE == 2) {
                    const float v = acc[i][j][r] + bias[row];
                    const int jc = (col & ~63) | ((((col >> 3) & 7) ^ (row & 7)) << 3)
                                 | (col & 7);
                    ((unsigned short*)Y)[(size_t)row * ldy + jc] = f2bf(v);
                } else {
                    const float v = acc[i][j][r] + bias[col];
                    if constexpr (MODE == 0)
                        ((unsigned short*)Y)[(size_t)row * ldy + col] = f2bf(v);
                    else
                        ((float*)Y)[(size_t)row * ldy + col] = v;
                }
            }
        }
    }
}

// grid (24, 32): nblk<16 -> Q/K into qkbuf; nblk>=16 -> V^T GEMM into VT.
__global__ __launch_bounds__(256)
void qkv_proj(const unsigned short* __restrict__ ws,
              const float* __restrict__ bq, const float* __restrict__ bk,
              const float* __restrict__ bv,
              unsigned short* __restrict__ qk, unsigned short* __restrict__ vt)
{
    const int nblk = blockIdx.x;
    if (nblk < 16) {
        const int mat  = nblk >> 3;                 // 0=Q 1=K
        const int ncol = (nblk & 7) * 128;
        const int m0   = blockIdx.y * 128;
        const unsigned short* A = ws + (size_t)mat * 4 * MEG + (size_t)m0 * 1024;
        const unsigned short* W = ws + (size_t)12 * MEG + (size_t)mat * MEG
                                     + (size_t)ncol * 1024;
        const float* bias = ((mat == 0) ? bq : bk) + ncol;
        gemm_mfma_core<0>(A, W, bias,
                          qk + (size_t)m0 * 2048 + mat * 1024 + ncol, 2048);
    } else {
        // V^T[b] = w_v @ x_v[b]^T : A = w_v rows(dims), W = x_v[b] rows(tokens)
        const int rowblk = nblk - 16;               // 0..7 (dim block)
        const int b      = blockIdx.y >> 4;
        const int colblk = blockIdx.y & 15;         // token block
        const unsigned short* A = ws + (size_t)14 * MEG + (size_t)rowblk * 128 * 1024;
        const unsigned short* W = ws + (size_t)8 * MEG + (size_t)b * 2 * MEG
                                     + (size_t)colblk * 128 * 1024;
        gemm_mfma_core<2>(A, W, bv + rowblk * 128,
                          vt + (size_t)b * 1024 * 2048
                             + (size_t)rowblk * 128 * 2048 + colblk * 128, 2048);
    }
}

__global__ __launch_bounds__(256)
void out_proj(const unsigned short* __restrict__ ws,
              const float* __restrict__ bo, float* __restrict__ out)
{
    const int n0 = blockIdx.x * 128;
    const int m0 = blockIdx.y * 128;
    const unsigned short* A = ws + (size_t)28 * MEG + (size_t)m0 * 1024;
    const unsigned short* W = ws + (size_t)15 * MEG + (size_t)n0 * 1024;
    gemm_mfma_core<1>(A, W, bo + n0, out + (size_t)m0 * 1024 + n0, 1024);
}

// ---------------------------------------------------------------------------
// MFMA flash attention v3:
//  - grid (bh=32, pair=16); block handles q-tiles {pair, 31-pair} -> uniform
//    33 k-tile-units per block (perfect CU balance, no tail).
//  - swapped QK^T: sf = mfma(K,Q) gives S^T (col=q=lo, row=key); key-reduce
//    is 15 local ops + 2 shuffles instead of 4 rows x 8 serial shuffles.
//  - double-buffered K/V staging with counted vmcnt(4) (loads span barriers).
// ---------------------------------------------------------------------------
__global__ __launch_bounds__(256)
void attn_mfma(const unsigned short* __restrict__ qk,
               const unsigned short* __restrict__ vt,
               const int* __restrict__ vlen, unsigned short* __restrict__ aout)
{
    __shared__ unsigned short Ks[2][64 * 64];
    __shared__ unsigned short Vs[2][64 * 64];
    __shared__ unsigned short Ps[4][16][72];

    const int bh  = blockIdx.x;
    const int pr  = blockIdx.y;            // 0..15
    const int b   = bh >> 4;
    const int h   = bh & 15;
    const int vl  = vlen[b];
    const int tid = threadIdx.x;
    const int w    = tid >> 6;
    const int lane = tid & 63;
    const int lo   = lane & 15;
    const int g    = lane >> 4;

    const unsigned short* qbase = qk + (size_t)(b * SS) * 2048 + h * 64;
    const unsigned short* kbase = qbase + 1024;
    const unsigned short* vtb   = vt + (size_t)b * 1024 * 2048
                                     + (size_t)(h * 64) * 2048;

#pragma unroll
    for (int half = 0; half < 2; ++half) {
        const int qt = half ? (31 - pr) : pr;
        const int q0 = qt * 64;
        const int qg = q0 + w * 16 + lo;   // this lane's q row (swapped layout)

        const bf16x8 a0 = *(const bf16x8*)(qbase + (size_t)qg * 2048 + g * 8);
        const bf16x8 a1 = *(const bf16x8*)(qbase + (size_t)qg * 2048 + 32 + g * 8);

        float mR = -INFINITY, lR = 0.f;
        f32x4 of[4];
#pragma unroll
        for (int f = 0; f < 4; ++f) of[f] = (f32x4)0.f;

        const int kmax   = min(q0 + 64, vl);
        const int ntiles = (kmax + 63) >> 6;

        // prologue: stage tile 0 into buf 0
#pragma unroll
        for (int u = 0; u < 2; ++u) {
            const int e = w * 128 + u * 64 + lane;
            const int r = e >> 3, c = e & 7;
            GLD_LDS16(kbase + (size_t)r * 2048 + ((c ^ (r & 7)) * 8),
                      &Ks[0][e * 8]);
            GLD_LDS16(vtb + (size_t)r * 2048 + c * 8, &Vs[0][e * 8]);
        }

        for (int kt = 0; kt < ntiles; ++kt) {
            const int cur = kt & 1;
            const int k0  = kt * 64;
            if (kt + 1 < ntiles) {          // issue next tile's loads
                const int kn = k0 + 64;
#pragma unroll
                for (int u = 0; u < 2; ++u) {
                    const int e = w * 128 + u * 64 + lane;
                    const int r = e >> 3, c = e & 7;
                    GLD_LDS16(kbase + (size_t)(kn + r) * 2048 + ((c ^ (r & 7)) * 8),
                              &Ks[cur ^ 1][e * 8]);
                    GLD_LDS16(vtb + (size_t)r * 2048 + kn + c * 8,
                              &Vs[cur ^ 1][e * 8]);
                }
                asm volatile("s_waitcnt vmcnt(4)" ::: "memory");
            } else {
                asm volatile("s_waitcnt vmcnt(0)" ::: "memory");
            }
            __syncthreads();               // cur buffer ready for all waves

            // S^T strip: sf[f] rows = keys f*16+g*4+r, col = q = lo
            f32x4 sf[4];
#pragma unroll
            for (int f = 0; f < 4; ++f) sf[f] = (f32x4)0.f;
#pragma unroll
            for (int f = 0; f < 4; ++f) {
                const int kr = f * 16 + lo;
                const bf16x8 kb0 = *(const bf16x8*)(&Ks[cur][kr * 64 + ((g ^ (lo & 7)) * 8)]);
                const bf16x8 kb1 = *(const bf16x8*)(&Ks[cur][kr * 64 + (((4 + g) ^ (lo & 7)) * 8)]);
                sf[f] = __builtin_amdgcn_mfma_f32_16x16x32_bf16(kb0, a0, sf[f], 0, 0, 0);
                sf[f] = __builtin_amdgcn_mfma_f32_16x16x32_bf16(kb1, a1, sf[f], 0, 0, 0);
            }

            // per-lane softmax over 16 local keys + 2-shuffle cross-group
            const bool full = (k0 + 63 <= q0 + w * 16) && (k0 + 64 <= vl);
            float sv[16];
            float t = -INFINITY;
#pragma unroll
            for (int f = 0; f < 4; ++f)
#pragma unroll
                for (int r = 0; r < 4; ++r) {
                    float x = sf[f][r] * 0.125f;
                    if (!full) {
                        const int kg = k0 + f * 16 + g * 4 + r;
                        x = (kg <= qg && kg < vl) ? x : -INFINITY;
                    }
                    sv[f * 4 + r] = x;
                    t = fmaxf(t, x);
                }
            t = fmaxf(t, __shfl_xor(t, 16));
            t = fmaxf(t, __shfl_xor(t, 32));
            const float mn   = fmaxf(mR, t);
            const float corr = __expf(mR - mn);
            float ps = 0.f;
#pragma unroll
            for (int f = 0; f < 4; ++f) {
                const float p0 = __expf(sv[f * 4 + 0] - mn);
                const float p1 = __expf(sv[f * 4 + 1] - mn);
                const float p2 = __expf(sv[f * 4 + 2] - mn);
                const float p3 = __expf(sv[f * 4 + 3] - mn);
                ps += (p0 + p1) + (p2 + p3);
                ushort4 pk;
                pk.x = f2bf(p0); pk.y = f2bf(p1); pk.z = f2bf(p2); pk.w = f2bf(p3);
                *(ushort4*)&Ps[w][lo][f * 16 + g * 4] = pk;   // ds_write_b64
            }
            ps += __shfl_xor(ps, 16);
            ps += __shfl_xor(ps, 32);
            lR = lR * corr + ps;
            mR = mn;

            // rescale O: of[.][r] is q-row g*4+r; its corr lives in lane g*4+r
            float crs[4];
#pragma unroll
            for (int r = 0; r < 4; ++r) crs[r] = __shfl(corr, g * 4 + r);
#pragma unroll
            for (int f = 0; f < 4; ++f)
#pragma unroll
                for (int r = 0; r < 4; ++r) of[f][r] *= crs[r];

            // O += P V
#pragma unroll
            for (int kk = 0; kk < 2; ++kk) {
                const bf16x8 pa = *(const bf16x8*)&Ps[w][lo][kk * 32 + g * 8];
#pragma unroll
                for (int f = 0; f < 4; ++f) {
                    const bf16x8 vb = *(const bf16x8*)(&Vs[cur][(f * 16 + lo) * 64
                                        + (((4 * kk + g) ^ (lo & 7)) * 8)]);
                    of[f] = __builtin_amdgcn_mfma_f32_16x16x32_bf16(pa, vb, of[f], 0, 0, 0);
                }
            }
            __syncthreads();               // cur fully consumed before restage
        }

        // epilogue: l for q-row g*4+r lives in lane g*4+r
        float rv[4];
#pragma unroll
        for (int r = 0; r < 4; ++r) rv[r] = 1.0f / __shfl(lR, g * 4 + r);
        unsigned short* ob = aout + (size_t)(b * SS + q0 + w * 16) * 1024 + h * 64;
#pragma unroll
        for (int f = 0; f < 4; ++f)
#pragma unroll
            for (int r = 0; r < 4; ++r)
                ob[(size_t)(g * 4 + r) * 1024 + f * 16 + lo] = f2bf(of[f][r] * rv[r]);
    }
}

extern "C" void kernel_launch(void* const* d_in, const int* in_sizes, int n_in,
                              void* d_out, int out_size, void* d_ws, size_t ws_size,
                              hipStream_t stream) {
    const float* xq = (const float*)d_in[0];
    const float* xk = (const float*)d_in[1];
    const float* xv = (const float*)d_in[2];
    const int*   vl = (const int*)  d_in[3];
    const float* wq = (const float*)d_in[4];
    const float* bq = (const float*)d_in[5];
    const float* wk = (const float*)d_in[6];
    const float* bk = (const float*)d_in[7];
    const float* wv = (const float*)d_in[8];
    const float* bv = (const float*)d_in[9];
    const float* wo = (const float*)d_in[10];
    const float* bo = (const float*)d_in[11];

    unsigned short* ws     = (unsigned short*)d_ws;
    unsigned short* qkbuf  = ws + (size_t)16 * MEG;
    unsigned short* vtbuf  = ws + (size_t)24 * MEG;
    unsigned short* abuf   = ws + (size_t)28 * MEG;

    cvt_all<<<dim3(2048, 7), 256, 0, stream>>>(xq, xk, xv, wq, wk, wv, wo, ws);
    qkv_proj<<<dim3(24, 32), 256, 0, stream>>>(ws, bq, bk, bv, qkbuf, vtbuf);
    attn_mfma<<<dim3(BB * NH, 16), 256, 0, stream>>>(qkbuf, vtbuf, vl, abuf);
    out_proj<<<dim3(8, 32), 256, 0, stream>>>(ws, bo, (float*)d_out);
}

// Round 6
// 138.033 us; speedup vs baseline: 12.4095x; 1.0909x over previous
//
#include <hip/hip_runtime.h>
#include <math.h>

#define NH 16
#define HD 64
#define DM 1024
#define BB 2
#define SS 2048
#define MROWS (BB*SS)   // 4096
#define MEG 1048576

typedef __attribute__((ext_vector_type(8))) short bf16x8;
typedef __attribute__((ext_vector_type(4))) float f32x4;

__device__ __forceinline__ unsigned short f2bf(float x) {
    unsigned int u = __float_as_uint(x);
    u += 0x7fff + ((u >> 16) & 1);          // round-to-nearest-even
    return (unsigned short)(u >> 16);
}

#define GLD_LDS16(gp, lp) __builtin_amdgcn_global_load_lds(                  \
        (const __attribute__((address_space(1))) void*)(gp),                 \
        (__attribute__((address_space(3))) void*)(lp), 16, 0, 0)

// ---------------------------------------------------------------------------
// ws layout (bf16 elements):
//   0   : xqb (4M)   4M: xkb   8M: xvb
//   12M : wqb (1M)  13M: wkb  14M: wvb  15M: wob
//   16M : qkbuf (8M)  [4096][2048]  (Q cols 0..1023, K cols 1024..2047)
//   24M : VT (4M)     [2][1024][2048]  V^T per batch, token-chunk swizzled
//   28M : abuf (4M)   [4096][1024]
// ---------------------------------------------------------------------------
__global__ __launch_bounds__(256)
void cvt_all(const float* __restrict__ xq, const float* __restrict__ xk,
             const float* __restrict__ xv, const float* __restrict__ wq,
             const float* __restrict__ wk, const float* __restrict__ wv,
             const float* __restrict__ wo, unsigned short* __restrict__ ws)
{
    const int reg = blockIdx.y;                       // 0..6
    const size_t n    = (reg < 3) ? (size_t)4 * MEG : (size_t)MEG;
    const size_t roff = (reg < 3) ? (size_t)reg * 4 * MEG
                                  : (size_t)12 * MEG + (size_t)(reg - 3) * MEG;
    const float* src = (reg == 0) ? xq : (reg == 1) ? xk : (reg == 2) ? xv :
                       (reg == 3) ? wq : (reg == 4) ? wk : (reg == 5) ? wv : wo;
    const size_t i = ((size_t)blockIdx.x * 256 + threadIdx.x) * 8;
    if (i >= n) return;
    const float4 a = *(const float4*)(src + i);
    const float4 b = *(const float4*)(src + i + 4);
    ushort4 lo4, hi4;
    lo4.x = f2bf(a.x); lo4.y = f2bf(a.y); lo4.z = f2bf(a.z); lo4.w = f2bf(a.w);
    hi4.x = f2bf(b.x); hi4.y = f2bf(b.y); hi4.z = f2bf(b.z); hi4.w = f2bf(b.w);
    *(ushort4*)(ws + roff + i)     = lo4;
    *(ushort4*)(ws + roff + i + 4) = hi4;
}

// ---------------------------------------------------------------------------
// bf16 MFMA GEMM (m97 structure): D[m][n] = sum_k A[m][k]*W[n][k] (+bias)
// 128x128 tile, BK=64, 4 waves in 2x2, each 64x64 out (4x4 frags 16x16x32).
// MODE 0: bf16 out, col-bias.  MODE 1: f32 out, col-bias.
// MODE 2: bf16 out, ROW-bias, token-chunk XOR swizzle on col (V^T producer).
// ---------------------------------------------------------------------------
template<int MODE>
__device__ __forceinline__ void gemm_mfma_core(
    const unsigned short* __restrict__ A,
    const unsigned short* __restrict__ W,
    const float* __restrict__ bias,
    void* __restrict__ Y, int ldy)
{
    __shared__ unsigned short As[128 * 64];
    __shared__ unsigned short Bs[128 * 64];

    const int tid  = threadIdx.x;
    const int w    = tid >> 6;
    const int lane = tid & 63;
    const int lo   = lane & 15;
    const int g    = lane >> 4;
    const int wr   = (w >> 1) * 64;
    const int wc   = (w & 1) * 64;

    f32x4 acc[4][4];
#pragma unroll
    for (int i = 0; i < 4; ++i)
#pragma unroll
        for (int j = 0; j < 4; ++j) acc[i][j] = (f32x4)0.f;

    for (int k0 = 0; k0 < 1024; k0 += 64) {
        __syncthreads();
#pragma unroll
        for (int u = 0; u < 4; ++u) {
            const int e   = (u * 256 + tid) * 8;
            const int row = e >> 6, col = e & 63;
            GLD_LDS16(A + (size_t)row * 1024 + k0 + col, As + e);
            GLD_LDS16(W + (size_t)row * 1024 + k0 + col, Bs + e);
        }
        asm volatile("s_waitcnt vmcnt(0)" ::: "memory");
        __syncthreads();

#pragma unroll
        for (int kk = 0; kk < 2; ++kk) {
            bf16x8 af[4], bf[4];
#pragma unroll
            for (int i = 0; i < 4; ++i) {
                af[i] = *(const bf16x8*)(As + (wr + i * 16 + lo) * 64 + kk * 32 + g * 8);
                bf[i] = *(const bf16x8*)(Bs + (wc + i * 16 + lo) * 64 + kk * 32 + g * 8);
            }
#pragma unroll
            for (int i = 0; i < 4; ++i)
#pragma unroll
                for (int j = 0; j < 4; ++j)
                    acc[i][j] = __builtin_amdgcn_mfma_f32_16x16x32_bf16(
                        af[i], bf[j], acc[i][j], 0, 0, 0);
        }
    }

#pragma unroll
    for (int i = 0; i < 4; ++i) {
#pragma unroll
        for (int j = 0; j < 4; ++j) {
            const int col = wc + j * 16 + lo;
#pragma unroll
            for (int r = 0; r < 4; ++r) {
                const int row = wr + i * 16 + g * 4 + r;
                if constexpr (MODE == 2) {
                    const float v = acc[i][j][r] + bias[row];
                    const int jc = (col & ~63) | ((((col >> 3) & 7) ^ (row & 7)) << 3)
                                 | (col & 7);
                    ((unsigned short*)Y)[(size_t)row * ldy + jc] = f2bf(v);
                } else {
                    const float v = acc[i][j][r] + bias[col];
                    if constexpr (MODE == 0)
                        ((unsigned short*)Y)[(size_t)row * ldy + col] = f2bf(v);
                    else
                        ((float*)Y)[(size_t)row * ldy + col] = v;
                }
            }
        }
    }
}

// grid (24, 32): nblk<16 -> Q/K into qkbuf; nblk>=16 -> V^T GEMM into VT.
__global__ __launch_bounds__(256)
void qkv_proj(const unsigned short* __restrict__ ws,
              const float* __restrict__ bq, const float* __restrict__ bk,
              const float* __restrict__ bv,
              unsigned short* __restrict__ qk, unsigned short* __restrict__ vt)
{
    const int nblk = blockIdx.x;
    if (nblk < 16) {
        const int mat  = nblk >> 3;                 // 0=Q 1=K
        const int ncol = (nblk & 7) * 128;
        const int m0   = blockIdx.y * 128;
        const unsigned short* A = ws + (size_t)mat * 4 * MEG + (size_t)m0 * 1024;
        const unsigned short* W = ws + (size_t)12 * MEG + (size_t)mat * MEG
                                     + (size_t)ncol * 1024;
        const float* bias = ((mat == 0) ? bq : bk) + ncol;
        gemm_mfma_core<0>(A, W, bias,
                          qk + (size_t)m0 * 2048 + mat * 1024 + ncol, 2048);
    } else {
        // V^T[b] = w_v @ x_v[b]^T : A = w_v rows(dims), W = x_v[b] rows(tokens)
        const int rowblk = nblk - 16;               // 0..7 (dim block)
        const int b      = blockIdx.y >> 4;
        const int colblk = blockIdx.y & 15;         // token block
        const unsigned short* A = ws + (size_t)14 * MEG + (size_t)rowblk * 128 * 1024;
        const unsigned short* W = ws + (size_t)8 * MEG + (size_t)b * 2 * MEG
                                     + (size_t)colblk * 128 * 1024;
        gemm_mfma_core<2>(A, W, bv + rowblk * 128,
                          vt + (size_t)b * 1024 * 2048
                             + (size_t)rowblk * 128 * 2048 + colblk * 128, 2048);
    }
}

__global__ __launch_bounds__(256)
void out_proj(const unsigned short* __restrict__ ws,
              const float* __restrict__ bo, float* __restrict__ out)
{
    const int n0 = blockIdx.x * 128;
    const int m0 = blockIdx.y * 128;
    const unsigned short* A = ws + (size_t)28 * MEG + (size_t)m0 * 1024;
    const unsigned short* W = ws + (size_t)15 * MEG + (size_t)n0 * 1024;
    gemm_mfma_core<1>(A, W, bo + n0, out + (size_t)m0 * 1024 + n0, 1024);
}

// ---------------------------------------------------------------------------
// MFMA flash attention v4:
//  - grid (bh=32, qt=32), heavy q-tiles first; 1024 blocks -> dynamic refill
//    absorbs valid_len imbalance. LDS exactly 40KB -> 4 blocks/CU (16 waves).
//  - swapped QK^T (S^T) AND swapped PV: O kept transposed (row=dim, col=q),
//    so corr/l are lane-uniform -> zero cross-lane ops outside the 4 reduce
//    shuffles. Defer-max skips rescale when max doesn't grow (T13).
//  - double-buffered K/V via global_load_lds, counted vmcnt(4); setprio
//    around MFMA clusters (T5).
// ---------------------------------------------------------------------------
__global__ __launch_bounds__(256)
void attn_mfma(const unsigned short* __restrict__ qk,
               const unsigned short* __restrict__ vt,
               const int* __restrict__ vlen, unsigned short* __restrict__ aout)
{
    __shared__ unsigned short Ks[2][64 * 64];
    __shared__ unsigned short Vs[2][64 * 64];
    __shared__ unsigned short Ps[4][16 * 64];   // per-wave P, chunk-XOR swizzled

    const int bh  = blockIdx.x;
    const int qt  = 31 - blockIdx.y;       // heavy tiles dispatch first
    const int b   = bh >> 4;
    const int h   = bh & 15;
    const int q0  = qt * 64;
    const int vl  = vlen[b];
    const int tid = threadIdx.x;
    const int w    = tid >> 6;
    const int lane = tid & 63;
    const int lo   = lane & 15;
    const int g    = lane >> 4;
    const int lx   = lo & 7;               // XOR swizzle key

    const unsigned short* qbase = qk + (size_t)(b * SS) * 2048 + h * 64;
    const unsigned short* kbase = qbase + 1024;
    const unsigned short* vtb   = vt + (size_t)b * 1024 * 2048
                                     + (size_t)(h * 64) * 2048;

    const int qg = q0 + w * 16 + lo;       // this lane's q row
    const bf16x8 a0 = *(const bf16x8*)(qbase + (size_t)qg * 2048 + g * 8);
    const bf16x8 a1 = *(const bf16x8*)(qbase + (size_t)qg * 2048 + 32 + g * 8);

    float mR = -INFINITY, lR = 0.f;
    f32x4 of[4];
#pragma unroll
    for (int f = 0; f < 4; ++f) of[f] = (f32x4)0.f;

    const int kmax   = min(q0 + 64, vl);
    const int ntiles = (kmax + 63) >> 6;   // >= 1

    // prologue: stage tile 0 into buf 0
#pragma unroll
    for (int u = 0; u < 2; ++u) {
        const int e = w * 128 + u * 64 + lane;
        const int r = e >> 3, c = e & 7;
        GLD_LDS16(kbase + (size_t)r * 2048 + ((c ^ (r & 7)) * 8), &Ks[0][e * 8]);
        GLD_LDS16(vtb + (size_t)r * 2048 + c * 8, &Vs[0][e * 8]);
    }

    unsigned short* const Psw = Ps[w];

    for (int kt = 0; kt < ntiles; ++kt) {
        const int cur = kt & 1;
        const int k0  = kt * 64;
        if (kt + 1 < ntiles) {             // issue next tile's loads
            const int kn = k0 + 64;
#pragma unroll
            for (int u = 0; u < 2; ++u) {
                const int e = w * 128 + u * 64 + lane;
                const int r = e >> 3, c = e & 7;
                GLD_LDS16(kbase + (size_t)(kn + r) * 2048 + ((c ^ (r & 7)) * 8),
                          &Ks[cur ^ 1][e * 8]);
                GLD_LDS16(vtb + (size_t)r * 2048 + kn + c * 8, &Vs[cur ^ 1][e * 8]);
            }
            asm volatile("s_waitcnt vmcnt(4)" ::: "memory");
        } else {
            asm volatile("s_waitcnt vmcnt(0)" ::: "memory");
        }
        __syncthreads();                   // cur buffer ready for all waves

        // S^T strip: sf[f] rows = keys f*16+g*4+r, col = q = lo
        f32x4 sf[4];
#pragma unroll
        for (int f = 0; f < 4; ++f) sf[f] = (f32x4)0.f;
        __builtin_amdgcn_s_setprio(1);
#pragma unroll
        for (int f = 0; f < 4; ++f) {
            const int kr = f * 16 + lo;
            const bf16x8 kb0 = *(const bf16x8*)(&Ks[cur][kr * 64 + ((g ^ lx) * 8)]);
            const bf16x8 kb1 = *(const bf16x8*)(&Ks[cur][kr * 64 + (((4 + g) ^ lx) * 8)]);
            sf[f] = __builtin_amdgcn_mfma_f32_16x16x32_bf16(kb0, a0, sf[f], 0, 0, 0);
            sf[f] = __builtin_amdgcn_mfma_f32_16x16x32_bf16(kb1, a1, sf[f], 0, 0, 0);
        }
        __builtin_amdgcn_s_setprio(0);

        // per-lane softmax over 16 local keys + 2-shuffle cross-group reduce
        const bool full = (k0 + 63 <= q0 + w * 16) && (k0 + 64 <= vl);
        float sv[16];
        float t = -INFINITY;
#pragma unroll
        for (int f = 0; f < 4; ++f)
#pragma unroll
            for (int r = 0; r < 4; ++r) {
                float x = sf[f][r] * 0.125f;
                if (!full) {
                    const int kg = k0 + f * 16 + g * 4 + r;
                    x = (kg <= qg && kg < vl) ? x : -INFINITY;
                }
                sv[f * 4 + r] = x;
                t = fmaxf(t, x);
            }
        t = fmaxf(t, __shfl_xor(t, 16));
        t = fmaxf(t, __shfl_xor(t, 32));

        // defer-max: only rescale when the running max actually grows
        if (!__all(t <= mR + 8.f)) {
            const float mn   = fmaxf(mR, t);
            const float corr = __expf(mR - mn);
            lR *= corr;
#pragma unroll
            for (int f = 0; f < 4; ++f)
#pragma unroll
                for (int r = 0; r < 4; ++r) of[f][r] *= corr;
            mR = mn;
        }

        float ps = 0.f;
#pragma unroll
        for (int f = 0; f < 4; ++f) {
            const float p0 = __expf(sv[f * 4 + 0] - mR);
            const float p1 = __expf(sv[f * 4 + 1] - mR);
            const float p2 = __expf(sv[f * 4 + 2] - mR);
            const float p3 = __expf(sv[f * 4 + 3] - mR);
            ps += (p0 + p1) + (p2 + p3);
            ushort4 pk;
            pk.x = f2bf(p0); pk.y = f2bf(p1); pk.z = f2bf(p2); pk.w = f2bf(p3);
            // logical 8B granule f*4+g -> 16B chunk (f*2+(g>>1)) ^ lx, half g&1
            *(ushort4*)(Psw + lo * 64 + (((f * 2 + (g >> 1)) ^ lx) * 8)
                        + (g & 1) * 4) = pk;
        }
        ps += __shfl_xor(ps, 16);
        ps += __shfl_xor(ps, 32);
        lR += ps;

        // O^T += V^T P^T : of[f] rows = dims f*16+g*4+r, col = q = lo
        __builtin_amdgcn_s_setprio(1);
#pragma unroll
        for (int kk = 0; kk < 2; ++kk) {
            const bf16x8 pa = *(const bf16x8*)(Psw + lo * 64 + (((kk * 4 + g) ^ lx) * 8));
#pragma unroll
            for (int f = 0; f < 4; ++f) {
                const bf16x8 vb = *(const bf16x8*)(&Vs[cur][(f * 16 + lo) * 64
                                    + (((4 * kk + g) ^ lx) * 8)]);
                of[f] = __builtin_amdgcn_mfma_f32_16x16x32_bf16(vb, pa, of[f], 0, 0, 0);
            }
        }
        __builtin_amdgcn_s_setprio(0);
        __syncthreads();                   // cur fully consumed before restage
    }

    // epilogue: everything lane-uniform (q = lo); O^T[d][q] -> aout[q][d]
    const float rv = 1.0f / lR;
    unsigned short* ob = aout + (size_t)(b * SS + q0 + w * 16 + lo) * 1024 + h * 64;
#pragma unroll
    for (int f = 0; f < 4; ++f) {
        ushort4 ov;
        ov.x = f2bf(of[f][0] * rv);
        ov.y = f2bf(of[f][1] * rv);
        ov.z = f2bf(of[f][2] * rv);
        ov.w = f2bf(of[f][3] * rv);
        *(ushort4*)(ob + f * 16 + g * 4) = ov;
    }
}

extern "C" void kernel_launch(void* const* d_in, const int* in_sizes, int n_in,
                              void* d_out, int out_size, void* d_ws, size_t ws_size,
                              hipStream_t stream) {
    const float* xq = (const float*)d_in[0];
    const float* xk = (const float*)d_in[1];
    const float* xv = (const float*)d_in[2];
    const int*   vl = (const int*)  d_in[3];
    const float* wq = (const float*)d_in[4];
    const float* bq = (const float*)d_in[5];
    const float* wk = (const float*)d_in[6];
    const float* bk = (const float*)d_in[7];
    const float* wv = (const float*)d_in[8];
    const float* bv = (const float*)d_in[9];
    const float* wo = (const float*)d_in[10];
    const float* bo = (const float*)d_in[11];

    unsigned short* ws     = (unsigned short*)d_ws;
    unsigned short* qkbuf  = ws + (size_t)16 * MEG;
    unsigned short* vtbuf  = ws + (size_t)24 * MEG;
    unsigned short* abuf   = ws + (size_t)28 * MEG;

    cvt_all<<<dim3(2048, 7), 256, 0, stream>>>(xq, xk, xv, wq, wk, wv, wo, ws);
    qkv_proj<<<dim3(24, 32), 256, 0, stream>>>(ws, bq, bk, bv, qkbuf, vtbuf);
    attn_mfma<<<dim3(BB * NH, SS / 64), 256, 0, stream>>>(qkbuf, vtbuf, vl, abuf);
    out_proj<<<dim3(8, 32), 256, 0, stream>>>(ws, bo, (float*)d_out);
}

// Round 7
// 130.159 us; speedup vs baseline: 13.1603x; 1.0605x over previous
//
#include <hip/hip_runtime.h>
#include <math.h>

#define NH 16
#define HD 64
#define DM 1024
#define BB 2
#define SS 2048
#define MROWS (BB*SS)   // 4096
#define MEG 1048576

typedef __attribute__((ext_vector_type(8))) short bf16x8;
typedef __attribute__((ext_vector_type(4))) float f32x4;

__device__ __forceinline__ unsigned short f2bf(float x) {
    unsigned int u = __float_as_uint(x);
    u += 0x7fff + ((u >> 16) & 1);          // round-to-nearest-even
    return (unsigned short)(u >> 16);
}

#define GLD_LDS16(gp, lp) __builtin_amdgcn_global_load_lds(                  \
        (const __attribute__((address_space(1))) void*)(gp),                 \
        (__attribute__((address_space(3))) void*)(lp), 16, 0, 0)

// ---------------------------------------------------------------------------
// ws layout (bf16 elements):
//   0   : xqb (4M)   4M: xkb   8M: xvb
//   12M : wqb (1M)  13M: wkb  14M: wvb  15M: wob
//   16M : qkbuf (8M)  [4096][2048]  (Q cols 0..1023, K cols 1024..2047)
//   24M : VT (4M)     [2][1024][2048]  V^T per batch, token-chunk swizzled
//   28M : abuf (4M)   [4096][1024]
// ---------------------------------------------------------------------------
__global__ __launch_bounds__(256)
void cvt_all(const float* __restrict__ xq, const float* __restrict__ xk,
             const float* __restrict__ xv, const float* __restrict__ wq,
             const float* __restrict__ wk, const float* __restrict__ wv,
             const float* __restrict__ wo, unsigned short* __restrict__ ws)
{
    const int reg = blockIdx.y;                       // 0..6
    const size_t n    = (reg < 3) ? (size_t)4 * MEG : (size_t)MEG;
    const size_t roff = (reg < 3) ? (size_t)reg * 4 * MEG
                                  : (size_t)12 * MEG + (size_t)(reg - 3) * MEG;
    const float* src = (reg == 0) ? xq : (reg == 1) ? xk : (reg == 2) ? xv :
                       (reg == 3) ? wq : (reg == 4) ? wk : (reg == 5) ? wv : wo;
    const size_t i = ((size_t)blockIdx.x * 256 + threadIdx.x) * 8;
    if (i >= n) return;
    const float4 a = *(const float4*)(src + i);
    const float4 b = *(const float4*)(src + i + 4);
    ushort4 lo4, hi4;
    lo4.x = f2bf(a.x); lo4.y = f2bf(a.y); lo4.z = f2bf(a.z); lo4.w = f2bf(a.w);
    hi4.x = f2bf(b.x); hi4.y = f2bf(b.y); hi4.z = f2bf(b.z); hi4.w = f2bf(b.w);
    *(ushort4*)(ws + roff + i)     = lo4;
    *(ushort4*)(ws + roff + i + 4) = hi4;
}

// ---------------------------------------------------------------------------
// bf16 MFMA GEMM core: D[m][n] = sum_k A[m][k]*W[n][k] (+bias)
// 128x128 tile, BK=64, 4 waves in 2x2, each 64x64 out (4x4 frags 16x16x32).
// LDS tiles are PASSED IN (single 32KB allocation per kernel — avoids the
// 2x duplication when a kernel has two call sites). Chunk-XOR swizzle on
// the staging source + fragment reads: 16-way bank conflict -> 2-way (free).
// MODE 0: bf16 out, col-bias.  MODE 1: f32 out, col-bias.
// MODE 2: bf16 out, ROW-bias, token-chunk XOR swizzle on col (V^T producer).
// ---------------------------------------------------------------------------
template<int MODE>
__device__ __forceinline__ void gemm_mfma_core(
    const unsigned short* __restrict__ A,
    const unsigned short* __restrict__ W,
    const float* __restrict__ bias,
    void* __restrict__ Y, int ldy,
    unsigned short* __restrict__ As,     // [128*64] LDS
    unsigned short* __restrict__ Bs)     // [128*64] LDS
{
    const int tid  = threadIdx.x;
    const int w    = tid >> 6;
    const int lane = tid & 63;
    const int lo   = lane & 15;
    const int g    = lane >> 4;
    const int wr   = (w >> 1) * 64;
    const int wc   = (w & 1) * 64;

    f32x4 acc[4][4];
#pragma unroll
    for (int i = 0; i < 4; ++i)
#pragma unroll
        for (int j = 0; j < 4; ++j) acc[i][j] = (f32x4)0.f;

    for (int k0 = 0; k0 < 1024; k0 += 64) {
        __syncthreads();
#pragma unroll
        for (int u = 0; u < 4; ++u) {
            const int ci  = u * 256 + tid;          // 16B chunk 0..1023
            const int row = ci >> 3, c = ci & 7;
            const int sc  = (c ^ (row & 7)) * 8;    // pre-swizzled source col
            GLD_LDS16(A + (size_t)row * 1024 + k0 + sc, As + ci * 8);
            GLD_LDS16(W + (size_t)row * 1024 + k0 + sc, Bs + ci * 8);
        }
        asm volatile("s_waitcnt vmcnt(0)" ::: "memory");
        __syncthreads();

#pragma unroll
        for (int kk = 0; kk < 2; ++kk) {
            bf16x8 af[4], bf[4];
#pragma unroll
            for (int i = 0; i < 4; ++i) {
                const int ra = wr + i * 16 + lo;
                const int rb = wc + i * 16 + lo;
                af[i] = *(const bf16x8*)(As + ra * 64 + (((kk * 4 + g) ^ (ra & 7)) * 8));
                bf[i] = *(const bf16x8*)(Bs + rb * 64 + (((kk * 4 + g) ^ (rb & 7)) * 8));
            }
#pragma unroll
            for (int i = 0; i < 4; ++i)
#pragma unroll
                for (int j = 0; j < 4; ++j)
                    acc[i][j] = __builtin_amdgcn_mfma_f32_16x16x32_bf16(
                        af[i], bf[j], acc[i][j], 0, 0, 0);
        }
    }

#pragma unroll
    for (int i = 0; i < 4; ++i) {
#pragma unroll
        for (int j = 0; j < 4; ++j) {
            const int col = wc + j * 16 + lo;
#pragma unroll
            for (int r = 0; r < 4; ++r) {
                const int row = wr + i * 16 + g * 4 + r;
                if constexpr (MODE == 2) {
                    const float v = acc[i][j][r] + bias[row];
                    const int jc = (col & ~63) | ((((col >> 3) & 7) ^ (row & 7)) << 3)
                                 | (col & 7);
                    ((unsigned short*)Y)[(size_t)row * ldy + jc] = f2bf(v);
                } else {
                    const float v = acc[i][j][r] + bias[col];
                    if constexpr (MODE == 0)
                        ((unsigned short*)Y)[(size_t)row * ldy + col] = f2bf(v);
                    else
                        ((float*)Y)[(size_t)row * ldy + col] = v;
                }
            }
        }
    }
}

// grid (24, 32): nblk<16 -> Q/K into qkbuf; nblk>=16 -> V^T GEMM into VT.
__global__ __launch_bounds__(256)
void qkv_proj(const unsigned short* __restrict__ ws,
              const float* __restrict__ bq, const float* __restrict__ bk,
              const float* __restrict__ bv,
              unsigned short* __restrict__ qk, unsigned short* __restrict__ vt)
{
    __shared__ unsigned short As[128 * 64];
    __shared__ unsigned short Bs[128 * 64];
    const int nblk = blockIdx.x;
    if (nblk < 16) {
        const int mat  = nblk >> 3;                 // 0=Q 1=K
        const int ncol = (nblk & 7) * 128;
        const int m0   = blockIdx.y * 128;
        const unsigned short* A = ws + (size_t)mat * 4 * MEG + (size_t)m0 * 1024;
        const unsigned short* W = ws + (size_t)12 * MEG + (size_t)mat * MEG
                                     + (size_t)ncol * 1024;
        const float* bias = ((mat == 0) ? bq : bk) + ncol;
        gemm_mfma_core<0>(A, W, bias,
                          qk + (size_t)m0 * 2048 + mat * 1024 + ncol, 2048, As, Bs);
    } else {
        // V^T[b] = w_v @ x_v[b]^T : A = w_v rows(dims), W = x_v[b] rows(tokens)
        const int rowblk = nblk - 16;               // 0..7 (dim block)
        const int b      = blockIdx.y >> 4;
        const int colblk = blockIdx.y & 15;         // token block
        const unsigned short* A = ws + (size_t)14 * MEG + (size_t)rowblk * 128 * 1024;
        const unsigned short* W = ws + (size_t)8 * MEG + (size_t)b * 2 * MEG
                                     + (size_t)colblk * 128 * 1024;
        gemm_mfma_core<2>(A, W, bv + rowblk * 128,
                          vt + (size_t)b * 1024 * 2048
                             + (size_t)rowblk * 128 * 2048 + colblk * 128, 2048,
                          As, Bs);
    }
}

__global__ __launch_bounds__(256)
void out_proj(const unsigned short* __restrict__ ws,
              const float* __restrict__ bo, float* __restrict__ out)
{
    __shared__ unsigned short As[128 * 64];
    __shared__ unsigned short Bs[128 * 64];
    const int n0 = blockIdx.x * 128;
    const int m0 = blockIdx.y * 128;
    const unsigned short* A = ws + (size_t)28 * MEG + (size_t)m0 * 1024;
    const unsigned short* W = ws + (size_t)15 * MEG + (size_t)n0 * 1024;
    gemm_mfma_core<1>(A, W, bo + n0, out + (size_t)m0 * 1024 + n0, 1024, As, Bs);
}

// ---------------------------------------------------------------------------
// MFMA flash attention v4 (unchanged from round 5).
// ---------------------------------------------------------------------------
__global__ __launch_bounds__(256)
void attn_mfma(const unsigned short* __restrict__ qk,
               const unsigned short* __restrict__ vt,
               const int* __restrict__ vlen, unsigned short* __restrict__ aout)
{
    __shared__ unsigned short Ks[2][64 * 64];
    __shared__ unsigned short Vs[2][64 * 64];
    __shared__ unsigned short Ps[4][16 * 64];   // per-wave P, chunk-XOR swizzled

    const int bh  = blockIdx.x;
    const int qt  = 31 - blockIdx.y;       // heavy tiles dispatch first
    const int b   = bh >> 4;
    const int h   = bh & 15;
    const int q0  = qt * 64;
    const int vl  = vlen[b];
    const int tid = threadIdx.x;
    const int w    = tid >> 6;
    const int lane = tid & 63;
    const int lo   = lane & 15;
    const int g    = lane >> 4;
    const int lx   = lo & 7;               // XOR swizzle key

    const unsigned short* qbase = qk + (size_t)(b * SS) * 2048 + h * 64;
    const unsigned short* kbase = qbase + 1024;
    const unsigned short* vtb   = vt + (size_t)b * 1024 * 2048
                                     + (size_t)(h * 64) * 2048;

    const int qg = q0 + w * 16 + lo;       // this lane's q row
    const bf16x8 a0 = *(const bf16x8*)(qbase + (size_t)qg * 2048 + g * 8);
    const bf16x8 a1 = *(const bf16x8*)(qbase + (size_t)qg * 2048 + 32 + g * 8);

    float mR = -INFINITY, lR = 0.f;
    f32x4 of[4];
#pragma unroll
    for (int f = 0; f < 4; ++f) of[f] = (f32x4)0.f;

    const int kmax   = min(q0 + 64, vl);
    const int ntiles = (kmax + 63) >> 6;   // >= 1

    // prologue: stage tile 0 into buf 0
#pragma unroll
    for (int u = 0; u < 2; ++u) {
        const int e = w * 128 + u * 64 + lane;
        const int r = e >> 3, c = e & 7;
        GLD_LDS16(kbase + (size_t)r * 2048 + ((c ^ (r & 7)) * 8), &Ks[0][e * 8]);
        GLD_LDS16(vtb + (size_t)r * 2048 + c * 8, &Vs[0][e * 8]);
    }

    unsigned short* const Psw = Ps[w];

    for (int kt = 0; kt < ntiles; ++kt) {
        const int cur = kt & 1;
        const int k0  = kt * 64;
        if (kt + 1 < ntiles) {             // issue next tile's loads
            const int kn = k0 + 64;
#pragma unroll
            for (int u = 0; u < 2; ++u) {
                const int e = w * 128 + u * 64 + lane;
                const int r = e >> 3, c = e & 7;
                GLD_LDS16(kbase + (size_t)(kn + r) * 2048 + ((c ^ (r & 7)) * 8),
                          &Ks[cur ^ 1][e * 8]);
                GLD_LDS16(vtb + (size_t)r * 2048 + kn + c * 8, &Vs[cur ^ 1][e * 8]);
            }
            asm volatile("s_waitcnt vmcnt(4)" ::: "memory");
        } else {
            asm volatile("s_waitcnt vmcnt(0)" ::: "memory");
        }
        __syncthreads();                   // cur buffer ready for all waves

        // S^T strip: sf[f] rows = keys f*16+g*4+r, col = q = lo
        f32x4 sf[4];
#pragma unroll
        for (int f = 0; f < 4; ++f) sf[f] = (f32x4)0.f;
        __builtin_amdgcn_s_setprio(1);
#pragma unroll
        for (int f = 0; f < 4; ++f) {
            const int kr = f * 16 + lo;
            const bf16x8 kb0 = *(const bf16x8*)(&Ks[cur][kr * 64 + ((g ^ lx) * 8)]);
            const bf16x8 kb1 = *(const bf16x8*)(&Ks[cur][kr * 64 + (((4 + g) ^ lx) * 8)]);
            sf[f] = __builtin_amdgcn_mfma_f32_16x16x32_bf16(kb0, a0, sf[f], 0, 0, 0);
            sf[f] = __builtin_amdgcn_mfma_f32_16x16x32_bf16(kb1, a1, sf[f], 0, 0, 0);
        }
        __builtin_amdgcn_s_setprio(0);

        // per-lane softmax over 16 local keys + 2-shuffle cross-group reduce
        const bool full = (k0 + 63 <= q0 + w * 16) && (k0 + 64 <= vl);
        float sv[16];
        float t = -INFINITY;
#pragma unroll
        for (int f = 0; f < 4; ++f)
#pragma unroll
            for (int r = 0; r < 4; ++r) {
                float x = sf[f][r] * 0.125f;
                if (!full) {
                    const int kg = k0 + f * 16 + g * 4 + r;
                    x = (kg <= qg && kg < vl) ? x : -INFINITY;
                }
                sv[f * 4 + r] = x;
                t = fmaxf(t, x);
            }
        t = fmaxf(t, __shfl_xor(t, 16));
        t = fmaxf(t, __shfl_xor(t, 32));

        // defer-max: only rescale when the running max actually grows
        if (!__all(t <= mR + 8.f)) {
            const float mn   = fmaxf(mR, t);
            const float corr = __expf(mR - mn);
            lR *= corr;
#pragma unroll
            for (int f = 0; f < 4; ++f)
#pragma unroll
                for (int r = 0; r < 4; ++r) of[f][r] *= corr;
            mR = mn;
        }

        float ps = 0.f;
#pragma unroll
        for (int f = 0; f < 4; ++f) {
            const float p0 = __expf(sv[f * 4 + 0] - mR);
            const float p1 = __expf(sv[f * 4 + 1] - mR);
            const float p2 = __expf(sv[f * 4 + 2] - mR);
            const float p3 = __expf(sv[f * 4 + 3] - mR);
            ps += (p0 + p1) + (p2 + p3);
            ushort4 pk;
            pk.x = f2bf(p0); pk.y = f2bf(p1); pk.z = f2bf(p2); pk.w = f2bf(p3);
            // logical 8B granule f*4+g -> 16B chunk (f*2+(g>>1)) ^ lx, half g&1
            *(ushort4*)(Psw + lo * 64 + (((f * 2 + (g >> 1)) ^ lx) * 8)
                        + (g & 1) * 4) = pk;
        }
        ps += __shfl_xor(ps, 16);
        ps += __shfl_xor(ps, 32);
        lR += ps;

        // O^T += V^T P^T : of[f] rows = dims f*16+g*4+r, col = q = lo
        __builtin_amdgcn_s_setprio(1);
#pragma unroll
        for (int kk = 0; kk < 2; ++kk) {
            const bf16x8 pa = *(const bf16x8*)(Psw + lo * 64 + (((kk * 4 + g) ^ lx) * 8));
#pragma unroll
            for (int f = 0; f < 4; ++f) {
                const bf16x8 vb = *(const bf16x8*)(&Vs[cur][(f * 16 + lo) * 64
                                    + (((4 * kk + g) ^ lx) * 8)]);
                of[f] = __builtin_amdgcn_mfma_f32_16x16x32_bf16(vb, pa, of[f], 0, 0, 0);
            }
        }
        __builtin_amdgcn_s_setprio(0);
        __syncthreads();                   // cur fully consumed before restage
    }

    // epilogue: everything lane-uniform (q = lo); O^T[d][q] -> aout[q][d]
    const float rv = 1.0f / lR;
    unsigned short* ob = aout + (size_t)(b * SS + q0 + w * 16 + lo) * 1024 + h * 64;
#pragma unroll
    for (int f = 0; f < 4; ++f) {
        ushort4 ov;
        ov.x = f2bf(of[f][0] * rv);
        ov.y = f2bf(of[f][1] * rv);
        ov.z = f2bf(of[f][2] * rv);
        ov.w = f2bf(of[f][3] * rv);
        *(ushort4*)(ob + f * 16 + g * 4) = ov;
    }
}

extern "C" void kernel_launch(void* const* d_in, const int* in_sizes, int n_in,
                              void* d_out, int out_size, void* d_ws, size_t ws_size,
                              hipStream_t stream) {
    const float* xq = (const float*)d_in[0];
    const float* xk = (const float*)d_in[1];
    const float* xv = (const float*)d_in[2];
    const int*   vl = (const int*)  d_in[3];
    const float* wq = (const float*)d_in[4];
    const float* bq = (const float*)d_in[5];
    const float* wk = (const float*)d_in[6];
    const float* bk = (const float*)d_in[7];
    const float* wv = (const float*)d_in[8];
    const float* bv = (const float*)d_in[9];
    const float* wo = (const float*)d_in[10];
    const float* bo = (const float*)d_in[11];

    unsigned short* ws     = (unsigned short*)d_ws;
    unsigned short* qkbuf  = ws + (size_t)16 * MEG;
    unsigned short* vtbuf  = ws + (size_t)24 * MEG;
    unsigned short* abuf   = ws + (size_t)28 * MEG;

    cvt_all<<<dim3(2048, 7), 256, 0, stream>>>(xq, xk, xv, wq, wk, wv, wo, ws);
    qkv_proj<<<dim3(24, 32), 256, 0, stream>>>(ws, bq, bk, bv, qkbuf, vtbuf);
    attn_mfma<<<dim3(BB * NH, SS / 64), 256, 0, stream>>>(qkbuf, vtbuf, vl, abuf);
    out_proj<<<dim3(8, 32), 256, 0, stream>>>(ws, bo, (float*)d_out);
}

// Round 8
// 125.864 us; speedup vs baseline: 13.6094x; 1.0341x over previous
//
#include <hip/hip_runtime.h>
#include <math.h>

#define NH 16
#define HD 64
#define DM 1024
#define BB 2
#define SS 2048
#define MROWS (BB*SS)   // 4096
#define MEG 1048576

typedef __attribute__((ext_vector_type(8))) short bf16x8;
typedef __attribute__((ext_vector_type(4))) float f32x4;

__device__ __forceinline__ unsigned short f2bf(float x) {
    unsigned int u = __float_as_uint(x);
    u += 0x7fff + ((u >> 16) & 1);          // round-to-nearest-even
    return (unsigned short)(u >> 16);
}

#define GLD_LDS16(gp, lp) __builtin_amdgcn_global_load_lds(                  \
        (const __attribute__((address_space(1))) void*)(gp),                 \
        (__attribute__((address_space(3))) void*)(lp), 16, 0, 0)

// ---------------------------------------------------------------------------
// ws layout (bf16 elements):
//   0   : xqb (4M)   4M: xkb   8M: xvb
//   12M : wqb (1M)  13M: wkb  14M: wvb  15M: wob
//   16M : qkbuf (8M)  [4096][2048]  (Q cols 0..1023, K cols 1024..2047)
//   24M : VT (4M)     [2][1024][2048]  V^T per batch, token-chunk swizzled
//   28M : abuf (4M)   [4096][1024]
// ---------------------------------------------------------------------------
__global__ __launch_bounds__(256)
void cvt_all(const float* __restrict__ xq, const float* __restrict__ xk,
             const float* __restrict__ xv, const float* __restrict__ wq,
             const float* __restrict__ wk, const float* __restrict__ wv,
             const float* __restrict__ wo, unsigned short* __restrict__ ws)
{
    const int reg = blockIdx.y;                       // 0..6
    const size_t n    = (reg < 3) ? (size_t)4 * MEG : (size_t)MEG;
    const size_t roff = (reg < 3) ? (size_t)reg * 4 * MEG
                                  : (size_t)12 * MEG + (size_t)(reg - 3) * MEG;
    const float* src = (reg == 0) ? xq : (reg == 1) ? xk : (reg == 2) ? xv :
                       (reg == 3) ? wq : (reg == 4) ? wk : (reg == 5) ? wv : wo;
    const size_t i = ((size_t)blockIdx.x * 256 + threadIdx.x) * 8;
    if (i >= n) return;
    const float4 a = *(const float4*)(src + i);
    const float4 b = *(const float4*)(src + i + 4);
    ushort4 lo4, hi4;
    lo4.x = f2bf(a.x); lo4.y = f2bf(a.y); lo4.z = f2bf(a.z); lo4.w = f2bf(a.w);
    hi4.x = f2bf(b.x); hi4.y = f2bf(b.y); hi4.z = f2bf(b.z); hi4.w = f2bf(b.w);
    *(ushort4*)(ws + roff + i)     = lo4;
    *(ushort4*)(ws + roff + i + 4) = hi4;
}

// ---------------------------------------------------------------------------
// bf16 MFMA GEMM core: D[m][n] = sum_k A[m][k]*W[n][k] (+bias)
// 128x128 tile, BK=64, 4 waves in 2x2, each 64x64 out (4x4 frags 16x16x32).
// LDS tiles passed in (single 32KB allocation per kernel). Chunk-XOR swizzle
// on staging source + fragment reads (conflict-free, verified r7: 0 conflicts).
// MODE 0: bf16 out, col-bias.  MODE 1: f32 out, col-bias.
// MODE 2: bf16 out, ROW-bias, token-chunk XOR swizzle on col (V^T producer).
// ---------------------------------------------------------------------------
template<int MODE>
__device__ __forceinline__ void gemm_mfma_core(
    const unsigned short* __restrict__ A,
    const unsigned short* __restrict__ W,
    const float* __restrict__ bias,
    void* __restrict__ Y, int ldy,
    unsigned short* __restrict__ As,     // [128*64] LDS
    unsigned short* __restrict__ Bs)     // [128*64] LDS
{
    const int tid  = threadIdx.x;
    const int w    = tid >> 6;
    const int lane = tid & 63;
    const int lo   = lane & 15;
    const int g    = lane >> 4;
    const int wr   = (w >> 1) * 64;
    const int wc   = (w & 1) * 64;

    f32x4 acc[4][4];
#pragma unroll
    for (int i = 0; i < 4; ++i)
#pragma unroll
        for (int j = 0; j < 4; ++j) acc[i][j] = (f32x4)0.f;

    for (int k0 = 0; k0 < 1024; k0 += 64) {
        __syncthreads();
#pragma unroll
        for (int u = 0; u < 4; ++u) {
            const int ci  = u * 256 + tid;          // 16B chunk 0..1023
            const int row = ci >> 3, c = ci & 7;
            const int sc  = (c ^ (row & 7)) * 8;    // pre-swizzled source col
            GLD_LDS16(A + (size_t)row * 1024 + k0 + sc, As + ci * 8);
            GLD_LDS16(W + (size_t)row * 1024 + k0 + sc, Bs + ci * 8);
        }
        asm volatile("s_waitcnt vmcnt(0)" ::: "memory");
        __syncthreads();

#pragma unroll
        for (int kk = 0; kk < 2; ++kk) {
            bf16x8 af[4], bf[4];
#pragma unroll
            for (int i = 0; i < 4; ++i) {
                const int ra = wr + i * 16 + lo;
                const int rb = wc + i * 16 + lo;
                af[i] = *(const bf16x8*)(As + ra * 64 + (((kk * 4 + g) ^ (ra & 7)) * 8));
                bf[i] = *(const bf16x8*)(Bs + rb * 64 + (((kk * 4 + g) ^ (rb & 7)) * 8));
            }
#pragma unroll
            for (int i = 0; i < 4; ++i)
#pragma unroll
                for (int j = 0; j < 4; ++j)
                    acc[i][j] = __builtin_amdgcn_mfma_f32_16x16x32_bf16(
                        af[i], bf[j], acc[i][j], 0, 0, 0);
        }
    }

#pragma unroll
    for (int i = 0; i < 4; ++i) {
#pragma unroll
        for (int j = 0; j < 4; ++j) {
            const int col = wc + j * 16 + lo;
#pragma unroll
            for (int r = 0; r < 4; ++r) {
                const int row = wr + i * 16 + g * 4 + r;
                if constexpr (MODE == 2) {
                    const float v = acc[i][j][r] + bias[row];
                    const int jc = (col & ~63) | ((((col >> 3) & 7) ^ (row & 7)) << 3)
                                 | (col & 7);
                    ((unsigned short*)Y)[(size_t)row * ldy + jc] = f2bf(v);
                } else {
                    const float v = acc[i][j][r] + bias[col];
                    if constexpr (MODE == 0)
                        ((unsigned short*)Y)[(size_t)row * ldy + col] = f2bf(v);
                    else
                        ((float*)Y)[(size_t)row * ldy + col] = v;
                }
            }
        }
    }
}

// ---------------------------------------------------------------------------
// qkv_proj, XCD-chunked flat grid (768 blocks):
//  96 panel-groups x 8 sub-blocks. Group fg<64: (mat=fg>>5, m0) Q/K row-panel
//  shared by its 8 ncol sub-blocks. fg>=64: V^T (b,colblk) x_v-panel shared
//  by its 8 rowblk sub-blocks. xcd = wgid&7 (HW round-robin) gets groups
//  [12*xcd, 12*xcd+12) -> panel reuse is intra-XCD-L2; weights (2MB) stay
//  L2-resident. Cuts the 3.5x HBM over-fetch seen in r7 (104MB vs 30MB).
// ---------------------------------------------------------------------------
__global__ __launch_bounds__(256)
void qkv_proj(const unsigned short* __restrict__ ws,
              const float* __restrict__ bq, const float* __restrict__ bk,
              const float* __restrict__ bv,
              unsigned short* __restrict__ qk, unsigned short* __restrict__ vt)
{
    __shared__ unsigned short As[128 * 64];
    __shared__ unsigned short Bs[128 * 64];
    const int wg   = blockIdx.x;           // 0..767
    const int flat = (wg & 7) * 96 + (wg >> 3);
    const int fg   = flat >> 3;            // panel group 0..95
    const int sub  = flat & 7;             // sub-block within group
    const int mat  = fg >> 5;              // 0=Q 1=K 2=V^T
    const int r    = fg & 31;
    if (mat < 2) {
        const int m0   = r * 128;
        const int ncol = sub * 128;
        const unsigned short* A = ws + (size_t)mat * 4 * MEG + (size_t)m0 * 1024;
        const unsigned short* W = ws + (size_t)12 * MEG + (size_t)mat * MEG
                                     + (size_t)ncol * 1024;
        const float* bias = ((mat == 0) ? bq : bk) + ncol;
        gemm_mfma_core<0>(A, W, bias,
                          qk + (size_t)m0 * 2048 + mat * 1024 + ncol, 2048, As, Bs);
    } else {
        // V^T[b] = w_v @ x_v[b]^T : A = w_v rows(dims), W = x_v[b] rows(tokens)
        const int b      = r >> 4;
        const int colblk = r & 15;          // token block (shared W-panel)
        const int rowblk = sub;             // dim block
        const unsigned short* A = ws + (size_t)14 * MEG + (size_t)rowblk * 128 * 1024;
        const unsigned short* W = ws + (size_t)8 * MEG + (size_t)b * 2 * MEG
                                     + (size_t)colblk * 128 * 1024;
        gemm_mfma_core<2>(A, W, bv + rowblk * 128,
                          vt + (size_t)b * 1024 * 2048
                             + (size_t)rowblk * 128 * 2048 + colblk * 128, 2048,
                          As, Bs);
    }
}

// out_proj, same XCD-chunked remap (256 blocks = 32 groups x 8).
__global__ __launch_bounds__(256)
void out_proj(const unsigned short* __restrict__ ws,
              const float* __restrict__ bo, float* __restrict__ out)
{
    __shared__ unsigned short As[128 * 64];
    __shared__ unsigned short Bs[128 * 64];
    const int wg   = blockIdx.x;           // 0..255
    const int flat = (wg & 7) * 32 + (wg >> 3);
    const int m0   = (flat >> 3) * 128;
    const int n0   = (flat & 7) * 128;
    const unsigned short* A = ws + (size_t)28 * MEG + (size_t)m0 * 1024;
    const unsigned short* W = ws + (size_t)15 * MEG + (size_t)n0 * 1024;
    gemm_mfma_core<1>(A, W, bo + n0, out + (size_t)m0 * 1024 + n0, 1024, As, Bs);
}

// ---------------------------------------------------------------------------
// MFMA flash attention v4 (unchanged from round 6).
// ---------------------------------------------------------------------------
__global__ __launch_bounds__(256)
void attn_mfma(const unsigned short* __restrict__ qk,
               const unsigned short* __restrict__ vt,
               const int* __restrict__ vlen, unsigned short* __restrict__ aout)
{
    __shared__ unsigned short Ks[2][64 * 64];
    __shared__ unsigned short Vs[2][64 * 64];
    __shared__ unsigned short Ps[4][16 * 64];   // per-wave P, chunk-XOR swizzled

    const int bh  = blockIdx.x;
    const int qt  = 31 - blockIdx.y;       // heavy tiles dispatch first
    const int b   = bh >> 4;
    const int h   = bh & 15;
    const int q0  = qt * 64;
    const int vl  = vlen[b];
    const int tid = threadIdx.x;
    const int w    = tid >> 6;
    const int lane = tid & 63;
    const int lo   = lane & 15;
    const int g    = lane >> 4;
    const int lx   = lo & 7;               // XOR swizzle key

    const unsigned short* qbase = qk + (size_t)(b * SS) * 2048 + h * 64;
    const unsigned short* kbase = qbase + 1024;
    const unsigned short* vtb   = vt + (size_t)b * 1024 * 2048
                                     + (size_t)(h * 64) * 2048;

    const int qg = q0 + w * 16 + lo;       // this lane's q row
    const bf16x8 a0 = *(const bf16x8*)(qbase + (size_t)qg * 2048 + g * 8);
    const bf16x8 a1 = *(const bf16x8*)(qbase + (size_t)qg * 2048 + 32 + g * 8);

    float mR = -INFINITY, lR = 0.f;
    f32x4 of[4];
#pragma unroll
    for (int f = 0; f < 4; ++f) of[f] = (f32x4)0.f;

    const int kmax   = min(q0 + 64, vl);
    const int ntiles = (kmax + 63) >> 6;   // >= 1

    // prologue: stage tile 0 into buf 0
#pragma unroll
    for (int u = 0; u < 2; ++u) {
        const int e = w * 128 + u * 64 + lane;
        const int r = e >> 3, c = e & 7;
        GLD_LDS16(kbase + (size_t)r * 2048 + ((c ^ (r & 7)) * 8), &Ks[0][e * 8]);
        GLD_LDS16(vtb + (size_t)r * 2048 + c * 8, &Vs[0][e * 8]);
    }

    unsigned short* const Psw = Ps[w];

    for (int kt = 0; kt < ntiles; ++kt) {
        const int cur = kt & 1;
        const int k0  = kt * 64;
        if (kt + 1 < ntiles) {             // issue next tile's loads
            const int kn = k0 + 64;
#pragma unroll
            for (int u = 0; u < 2; ++u) {
                const int e = w * 128 + u * 64 + lane;
                const int r = e >> 3, c = e & 7;
                GLD_LDS16(kbase + (size_t)(kn + r) * 2048 + ((c ^ (r & 7)) * 8),
                          &Ks[cur ^ 1][e * 8]);
                GLD_LDS16(vtb + (size_t)r * 2048 + kn + c * 8, &Vs[cur ^ 1][e * 8]);
            }
            asm volatile("s_waitcnt vmcnt(4)" ::: "memory");
        } else {
            asm volatile("s_waitcnt vmcnt(0)" ::: "memory");
        }
        __syncthreads();                   // cur buffer ready for all waves

        // S^T strip: sf[f] rows = keys f*16+g*4+r, col = q = lo
        f32x4 sf[4];
#pragma unroll
        for (int f = 0; f < 4; ++f) sf[f] = (f32x4)0.f;
        __builtin_amdgcn_s_setprio(1);
#pragma unroll
        for (int f = 0; f < 4; ++f) {
            const int kr = f * 16 + lo;
            const bf16x8 kb0 = *(const bf16x8*)(&Ks[cur][kr * 64 + ((g ^ lx) * 8)]);
            const bf16x8 kb1 = *(const bf16x8*)(&Ks[cur][kr * 64 + (((4 + g) ^ lx) * 8)]);
            sf[f] = __builtin_amdgcn_mfma_f32_16x16x32_bf16(kb0, a0, sf[f], 0, 0, 0);
            sf[f] = __builtin_amdgcn_mfma_f32_16x16x32_bf16(kb1, a1, sf[f], 0, 0, 0);
        }
        __builtin_amdgcn_s_setprio(0);

        // per-lane softmax over 16 local keys + 2-shuffle cross-group reduce
        const bool full = (k0 + 63 <= q0 + w * 16) && (k0 + 64 <= vl);
        float sv[16];
        float t = -INFINITY;
#pragma unroll
        for (int f = 0; f < 4; ++f)
#pragma unroll
            for (int r = 0; r < 4; ++r) {
                float x = sf[f][r] * 0.125f;
                if (!full) {
                    const int kg = k0 + f * 16 + g * 4 + r;
                    x = (kg <= qg && kg < vl) ? x : -INFINITY;
                }
                sv[f * 4 + r] = x;
                t = fmaxf(t, x);
            }
        t = fmaxf(t, __shfl_xor(t, 16));
        t = fmaxf(t, __shfl_xor(t, 32));

        // defer-max: only rescale when the running max actually grows
        if (!__all(t <= mR + 8.f)) {
            const float mn   = fmaxf(mR, t);
            const float corr = __expf(mR - mn);
            lR *= corr;
#pragma unroll
            for (int f = 0; f < 4; ++f)
#pragma unroll
                for (int r = 0; r < 4; ++r) of[f][r] *= corr;
            mR = mn;
        }

        float ps = 0.f;
#pragma unroll
        for (int f = 0; f < 4; ++f) {
            const float p0 = __expf(sv[f * 4 + 0] - mR);
            const float p1 = __expf(sv[f * 4 + 1] - mR);
            const float p2 = __expf(sv[f * 4 + 2] - mR);
            const float p3 = __expf(sv[f * 4 + 3] - mR);
            ps += (p0 + p1) + (p2 + p3);
            ushort4 pk;
            pk.x = f2bf(p0); pk.y = f2bf(p1); pk.z = f2bf(p2); pk.w = f2bf(p3);
            // logical 8B granule f*4+g -> 16B chunk (f*2+(g>>1)) ^ lx, half g&1
            *(ushort4*)(Psw + lo * 64 + (((f * 2 + (g >> 1)) ^ lx) * 8)
                        + (g & 1) * 4) = pk;
        }
        ps += __shfl_xor(ps, 16);
        ps += __shfl_xor(ps, 32);
        lR += ps;

        // O^T += V^T P^T : of[f] rows = dims f*16+g*4+r, col = q = lo
        __builtin_amdgcn_s_setprio(1);
#pragma unroll
        for (int kk = 0; kk < 2; ++kk) {
            const bf16x8 pa = *(const bf16x8*)(Psw + lo * 64 + (((kk * 4 + g) ^ lx) * 8));
#pragma unroll
            for (int f = 0; f < 4; ++f) {
                const bf16x8 vb = *(const bf16x8*)(&Vs[cur][(f * 16 + lo) * 64
                                    + (((4 * kk + g) ^ lx) * 8)]);
                of[f] = __builtin_amdgcn_mfma_f32_16x16x32_bf16(vb, pa, of[f], 0, 0, 0);
            }
        }
        __builtin_amdgcn_s_setprio(0);
        __syncthreads();                   // cur fully consumed before restage
    }

    // epilogue: everything lane-uniform (q = lo); O^T[d][q] -> aout[q][d]
    const float rv = 1.0f / lR;
    unsigned short* ob = aout + (size_t)(b * SS + q0 + w * 16 + lo) * 1024 + h * 64;
#pragma unroll
    for (int f = 0; f < 4; ++f) {
        ushort4 ov;
        ov.x = f2bf(of[f][0] * rv);
        ov.y = f2bf(of[f][1] * rv);
        ov.z = f2bf(of[f][2] * rv);
        ov.w = f2bf(of[f][3] * rv);
        *(ushort4*)(ob + f * 16 + g * 4) = ov;
    }
}

extern "C" void kernel_launch(void* const* d_in, const int* in_sizes, int n_in,
                              void* d_out, int out_size, void* d_ws, size_t ws_size,
                              hipStream_t stream) {
    const float* xq = (const float*)d_in[0];
    const float* xk = (const float*)d_in[1];
    const float* xv = (const float*)d_in[2];
    const int*   vl = (const int*)  d_in[3];
    const float* wq = (const float*)d_in[4];
    const float* bq = (const float*)d_in[5];
    const float* wk = (const float*)d_in[6];
    const float* bk = (const float*)d_in[7];
    const float* wv = (const float*)d_in[8];
    const float* bv = (const float*)d_in[9];
    const float* wo = (const float*)d_in[10];
    const float* bo = (const float*)d_in[11];

    unsigned short* ws     = (unsigned short*)d_ws;
    unsigned short* qkbuf  = ws + (size_t)16 * MEG;
    unsigned short* vtbuf  = ws + (size_t)24 * MEG;
    unsigned short* abuf   = ws + (size_t)28 * MEG;

    cvt_all<<<dim3(2048, 7), 256, 0, stream>>>(xq, xk, xv, wq, wk, wv, wo, ws);
    qkv_proj<<<dim3(768), 256, 0, stream>>>(ws, bq, bk, bv, qkbuf, vtbuf);
    attn_mfma<<<dim3(BB * NH, SS / 64), 256, 0, stream>>>(qkbuf, vtbuf, vl, abuf);
    out_proj<<<dim3(256), 256, 0, stream>>>(ws, bo, (float*)d_out);
}